// Round 1
// baseline (5628.706 us; speedup 1.0000x reference)
//
#include <hip/hip_runtime.h>
#include <hip/hip_bf16.h>

// DeepPoly MLP verifier (784->2048x4->10), fp32 baseline.
// Per layer i: forward matvec; for each bound chain {high,low}:
//   M=W_i, bias=b_i; for j=i-1..0: relu-backsub elementwise (+bias row-dot),
//   bias += M@b_j, M = M@W_j (GEMM); finally interval matvec vs low0/high0.
// Relu records (wl,wh,bhr) captured after each non-final layer.

#define MEAN_C 0.1307f
#define STD_C  0.3081f

// ---- workspace offsets (in floats) ----
#define OFF_X0    0          // x ping (2048)
#define OFF_X1    2048       // x pong (2048)
#define OFF_LOW0  4096       // 784 (padded to 1024)
#define OFF_HIGH0 5120       // 784 (padded to 1024)
#define OFF_WL    6144       // 4*2048
#define OFF_WH    14336      // 4*2048
#define OFF_BHR   22528      // 4*2048
#define OFF_LOWI  30720      // 2048
#define OFF_HIGHI 32768      // 2048
#define OFF_BIAS  34816      // 2048
#define OFF_M0    40960      // 2048*2048
#define OFF_M1    (40960 + 2048*2048)
// total = 40960 + 2*4194304 floats = ~33.7 MB

__device__ __forceinline__ float blockReduce256(float v) {
    #pragma unroll
    for (int o = 32; o > 0; o >>= 1) v += __shfl_down(v, o, 64);
    __shared__ float sred[4];
    int w = threadIdx.x >> 6;
    if ((threadIdx.x & 63) == 0) sred[w] = v;
    __syncthreads();
    float r = 0.f;
    if (threadIdx.x == 0) r = sred[0] + sred[1] + sred[2] + sred[3];
    return r;  // valid in thread 0 only
}

__global__ void k_norm(const float* __restrict__ x, const float* __restrict__ lo,
                       const float* __restrict__ hi, float* __restrict__ ws) {
    int i = blockIdx.x * blockDim.x + threadIdx.x;
    if (i < 784) {
        ws[OFF_X0 + i]    = (x[i]  - MEAN_C) / STD_C;
        ws[OFF_LOW0 + i]  = (lo[i] - MEAN_C) / STD_C;
        ws[OFF_HIGH0 + i] = (hi[i] - MEAN_C) / STD_C;
    }
}

// y[r] = W[r,:] . x + b[r]     (W row-major [n,k]); one block per row
__global__ void k_matvec(const float* __restrict__ W, const float* __restrict__ x,
                         const float* __restrict__ b, float* __restrict__ y, int k) {
    int r = blockIdx.x;
    const float* Wr = W + (size_t)r * k;
    float acc = 0.f;
    for (int c = threadIdx.x; c < k; c += 256) acc += Wr[c] * x[c];
    acc = blockReduce256(acc);
    if (threadIdx.x == 0) y[r] = acc + b[r];
}

// bias[r] += A[r,:] . b   (A row-major [n,k])
__global__ void k_biasmv(const float* __restrict__ A, const float* __restrict__ b,
                         float* __restrict__ bias, int k) {
    int r = blockIdx.x;
    const float* Ar = A + (size_t)r * k;
    float acc = 0.f;
    for (int c = threadIdx.x; c < k; c += 256) acc += Ar[c] * b[c];
    acc = blockReduce256(acc);
    if (threadIdx.x == 0) bias[r] += acc;
}

// In-place relu back-substitution on M [n, cols], plus bias row reduction.
// high chain: M'= M>0? M*wh : M*wl ; bias += max(M,0).bhr
// low  chain: M'= M>0? M*wl : M*wh ; bias += min(M,0).bhr
__global__ void k_relu_bs(float* __restrict__ M, int cols,
                          const float* __restrict__ wl, const float* __restrict__ wh,
                          const float* __restrict__ bhr, float* __restrict__ bias,
                          int is_high) {
    int r = blockIdx.x;
    float* Mr = M + (size_t)r * cols;
    float acc = 0.f;
    for (int c = threadIdx.x; c < cols; c += 256) {
        float m = Mr[c];
        float l = wl[c], h = wh[c], bb = bhr[c];
        float out, bc;
        if (is_high) { out = (m > 0.f) ? m * h : m * l; bc = fmaxf(m, 0.f) * bb; }
        else         { out = (m > 0.f) ? m * l : m * h; bc = fminf(m, 0.f) * bb; }
        Mr[c] = out;
        acc += bc;
    }
    acc = blockReduce256(acc);
    if (threadIdx.x == 0) bias[r] += acc;
}

// Interval matvec: out[r] = sum_c (M<0 ? M*opp : M*same) + bias[r]
// high: same=high0, opp=low0 ; low: same=low0, opp=high0
__global__ void k_fboxes(const float* __restrict__ M, int cols,
                         const float* __restrict__ bias,
                         const float* __restrict__ lo0, const float* __restrict__ hi0,
                         float* __restrict__ out, int is_high) {
    int r = blockIdx.x;
    const float* Mr = M + (size_t)r * cols;
    float acc = 0.f;
    for (int c = threadIdx.x; c < cols; c += 256) {
        float m = Mr[c];
        if (is_high) acc += (m < 0.f) ? m * lo0[c] : m * hi0[c];
        else         acc += (m < 0.f) ? m * hi0[c] : m * lo0[c];
    }
    acc = blockReduce256(acc);
    if (threadIdx.x == 0) out[r] = acc + bias[r];
}

// Capture relu relaxation diagonals, relu the forward activation in place.
__global__ void k_relu_rec(float* __restrict__ x, const float* __restrict__ lo,
                           const float* __restrict__ hi, float* __restrict__ wl,
                           float* __restrict__ wh, float* __restrict__ bhr, int n) {
    int i = blockIdx.x * blockDim.x + threadIdx.x;
    if (i < n) {
        float l = lo[i], h = hi[i];
        float vwl, vwh, vbh;
        if (h <= 0.f)      { vwl = 0.f; vwh = 0.f; vbh = 0.f; }
        else if (l >= 0.f) { vwl = 1.f; vwh = 1.f; vbh = 0.f; }
        else {
            float d = h - l;
            vwh = h / d;
            vbh = -(l * h) / d;
            vwl = (l * l > h * h) ? 0.f : 1.f;
        }
        wl[i] = vwl; wh[i] = vwh; bhr[i] = vbh;
        x[i] = fmaxf(x[i], 0.f);
    }
}

// C[M,N] = A[M,K] @ B[K,N], all row-major. 64x64 tile, BK=16, 4x4/thread.
#define BM 64
#define BN 64
#define BK 16
__global__ __launch_bounds__(256) void k_gemm(const float* __restrict__ A,
                                              const float* __restrict__ B,
                                              float* __restrict__ C,
                                              int M, int N, int K) {
    __shared__ float As[BK][BM + 1];
    __shared__ float Bs[BK][BN];
    int tid = threadIdx.x;
    int tx = tid & 15, ty = tid >> 4;
    int row0 = blockIdx.y * BM, col0 = blockIdx.x * BN;
    float acc[4][4] = {};
    for (int k0 = 0; k0 < K; k0 += BK) {
        #pragma unroll
        for (int i = 0; i < 4; i++) {
            int r = (tid >> 4) + i * 16;
            int k = tid & 15;
            int gr = row0 + r;
            float v = 0.f;
            if (gr < M) v = A[(size_t)gr * K + (k0 + k)];  // K % 16 == 0 always
            As[k][r] = v;
        }
        #pragma unroll
        for (int i = 0; i < 4; i++) {
            int k = (tid >> 6) + i * 4;
            int c = tid & 63;
            int gc = col0 + c;
            float v = 0.f;
            if (gc < N) v = B[(size_t)(k0 + k) * N + gc];
            Bs[k][c] = v;
        }
        __syncthreads();
        #pragma unroll
        for (int k = 0; k < BK; k++) {
            float a[4], bb[4];
            #pragma unroll
            for (int i = 0; i < 4; i++) a[i] = As[k][ty * 4 + i];
            #pragma unroll
            for (int j = 0; j < 4; j++) bb[j] = Bs[k][tx * 4 + j];
            #pragma unroll
            for (int i = 0; i < 4; i++)
                #pragma unroll
                for (int j = 0; j < 4; j++)
                    acc[i][j] += a[i] * bb[j];
        }
        __syncthreads();
    }
    #pragma unroll
    for (int i = 0; i < 4; i++) {
        int gr = row0 + ty * 4 + i;
        if (gr >= M) continue;
        #pragma unroll
        for (int j = 0; j < 4; j++) {
            int gc = col0 + tx * 4 + j;
            if (gc < N) C[(size_t)gr * N + gc] = acc[i][j];
        }
    }
}

extern "C" void kernel_launch(void* const* d_in, const int* in_sizes, int n_in,
                              void* d_out, int out_size, void* d_ws, size_t ws_size,
                              hipStream_t stream) {
    static const int FCsz[6] = {784, 2048, 2048, 2048, 2048, 10};
    const float* x_in  = (const float*)d_in[0];
    const float* lo_in = (const float*)d_in[1];
    const float* hi_in = (const float*)d_in[2];
    const float* W[5];
    const float* bv[5];
    for (int i = 0; i < 5; i++) {
        W[i]  = (const float*)d_in[3 + 2 * i];
        bv[i] = (const float*)d_in[4 + 2 * i];
    }
    float* ws = (float*)d_ws;
    float* out = (float*)d_out;

    k_norm<<<4, 256, 0, stream>>>(x_in, lo_in, hi_in, ws);

    float* xin  = ws + OFF_X0;
    float* xout = ws + OFF_X1;

    for (int i = 0; i < 5; i++) {
        int n = FCsz[i + 1];
        int kdim = FCsz[i];

        // forward: x_{i+1} = W_i @ x_i + b_i
        float* ydst = (i == 4) ? out : xout;
        k_matvec<<<n, 256, 0, stream>>>(W[i], xin, bv[i], ydst, kdim);

        // back-substitution for both bounds (high first, then low)
        for (int chain = 0; chain < 2; chain++) {
            int is_high = (chain == 0) ? 1 : 0;
            hipMemcpyAsync(ws + OFF_M0, W[i], (size_t)n * kdim * sizeof(float),
                           hipMemcpyDeviceToDevice, stream);
            hipMemcpyAsync(ws + OFF_BIAS, bv[i], (size_t)n * sizeof(float),
                           hipMemcpyDeviceToDevice, stream);
            float* cur = ws + OFF_M0;
            float* nxt = ws + OFF_M1;
            for (int j = i - 1; j >= 0; j--) {
                // relu_j: cols = FCsz[j+1] = 2048
                k_relu_bs<<<n, 256, 0, stream>>>(cur, 2048,
                                                 ws + OFF_WL + j * 2048,
                                                 ws + OFF_WH + j * 2048,
                                                 ws + OFF_BHR + j * 2048,
                                                 ws + OFF_BIAS, is_high);
                // bias += cur @ b_j
                k_biasmv<<<n, 256, 0, stream>>>(cur, bv[j], ws + OFF_BIAS, 2048);
                // cur = cur @ W_j   [n,2048]@[2048,FCsz[j]]
                int ncols = FCsz[j];
                dim3 g((ncols + BN - 1) / BN, (n + BM - 1) / BM);
                k_gemm<<<g, 256, 0, stream>>>(cur, W[j], nxt, n, ncols, 2048);
                float* t = cur; cur = nxt; nxt = t;
            }
            float* dest = (i == 4) ? (out + (is_high ? 20 : 10))
                                   : (ws + (is_high ? OFF_HIGHI : OFF_LOWI));
            k_fboxes<<<n, 256, 0, stream>>>(cur, 784, ws + OFF_BIAS,
                                            ws + OFF_LOW0, ws + OFF_HIGH0,
                                            dest, is_high);
        }

        if (i < 4) {
            k_relu_rec<<<(n + 255) / 256, 256, 0, stream>>>(
                ydst, ws + OFF_LOWI, ws + OFF_HIGHI,
                ws + OFF_WL + i * 2048, ws + OFF_WH + i * 2048,
                ws + OFF_BHR + i * 2048, n);
            float* t = xin; xin = xout; xout = t;
        }
    }
}

// Round 2
// 1572.168 us; speedup vs baseline: 3.5802x; 3.5802x over previous
//
#include <hip/hip_runtime.h>
#include <hip/hip_bf16.h>

// DeepPoly MLP verifier (784->2048x4->10).
// Backsub GEMMs run on bf16 MFMA (16x16x32) with hi/lo split, 3 products
// (hh + hl + lh) ~ fp32 accuracy. A (the running M matrix) is emitted as
// bf16 hi/lo by the fused relu-backsub kernel; B = W_j^T is transposed+split
// per use into a single Wt buffer (N padded to 896 for W0 so width-16
// global_load_lds needs no predication). Layer-5 chains (M=10) use a
// memory-bound fp32 split-K kernel.

#define MEAN_C 0.1307f
#define STD_C  0.3081f

// ---- workspace offsets (floats) ----
#define OFF_X0     0u          // 2048
#define OFF_X1     2048u
#define OFF_L0     4096u       // 784 used
#define OFF_H0     5120u
#define OFF_WL     6144u       // 4*2048
#define OFF_WH     14336u
#define OFF_BHR    22528u
#define OFF_LOWI   30720u
#define OFF_HIGHI  32768u
#define OFF_BIAS   34816u      // 2048
#define OFF_P0     36864u      // 10*2048
#define OFF_P1     57344u
#define OFF_C      77824u      // fp32 [2048, <=2048]
#define OFF_AHI    4272128u    // bf16 2048x2048 (as float halves)
#define OFF_ALO    6369280u
#define OFF_WTHI   8466432u    // bf16 [<=2048 n][2048 k]
#define OFF_WTLO   10563584u
// total 12660736 floats ~= 50.6 MB

typedef __bf16 bf16x8 __attribute__((ext_vector_type(8)));
typedef float floatx4 __attribute__((ext_vector_type(4)));

__device__ __forceinline__ void gl2lds16(const void* g, void* l) {
    __builtin_amdgcn_global_load_lds(
        (const __attribute__((address_space(1))) unsigned int*)g,
        (__attribute__((address_space(3))) unsigned int*)l, 16, 0, 0);
}

__device__ __forceinline__ float blockReduce256(float v) {
    #pragma unroll
    for (int o = 32; o > 0; o >>= 1) v += __shfl_down(v, o, 64);
    __shared__ float sred[4];
    int w = threadIdx.x >> 6;
    if ((threadIdx.x & 63) == 0) sred[w] = v;
    __syncthreads();
    float r = 0.f;
    if (threadIdx.x == 0) r = sred[0] + sred[1] + sred[2] + sred[3];
    return r;  // valid in thread 0 only
}

__global__ void k_norm(const float* __restrict__ x, const float* __restrict__ lo,
                       const float* __restrict__ hi, float* __restrict__ ws) {
    int i = blockIdx.x * blockDim.x + threadIdx.x;
    if (i < 784) {
        ws[OFF_X0 + i] = (x[i]  - MEAN_C) / STD_C;
        ws[OFF_L0 + i] = (lo[i] - MEAN_C) / STD_C;
        ws[OFF_H0 + i] = (hi[i] - MEAN_C) / STD_C;
    }
}

__global__ void k_matvec(const float* __restrict__ W, const float* __restrict__ x,
                         const float* __restrict__ b, float* __restrict__ y, int k) {
    int r = blockIdx.x;
    const float* Wr = W + (size_t)r * k;
    float acc = 0.f;
    for (int c = threadIdx.x; c < k; c += 256) acc += Wr[c] * x[c];
    acc = blockReduce256(acc);
    if (threadIdx.x == 0) y[r] = acc + b[r];
}

// Fused relu-backsub + bias (bhr dot + b_j dot) + bf16 hi/lo split of output.
__global__ void k_relu_split(const float* __restrict__ Min, int lda,
                             const float* __restrict__ wl, const float* __restrict__ wh,
                             const float* __restrict__ bhr, const float* __restrict__ bj,
                             float* __restrict__ bias, const float* __restrict__ bias_init,
                             __hip_bfloat16* __restrict__ Ahi, __hip_bfloat16* __restrict__ Alo,
                             int is_high) {
    int row = blockIdx.x;
    const float* Mr = Min + (size_t)row * lda;
    float acc = 0.f;
    for (int c = threadIdx.x; c < 2048; c += 256) {
        float m = Mr[c];
        float out, bt;
        if (is_high) { out = (m > 0.f) ? m * wh[c] : m * wl[c]; bt = fmaxf(m, 0.f) * bhr[c]; }
        else         { out = (m > 0.f) ? m * wl[c] : m * wh[c]; bt = fminf(m, 0.f) * bhr[c]; }
        acc += bt + out * bj[c];
        __hip_bfloat16 h = __float2bfloat16(out);
        Ahi[(size_t)row * 2048 + c] = h;
        Alo[(size_t)row * 2048 + c] = __float2bfloat16(out - __bfloat162float(h));
    }
    acc = blockReduce256(acc);
    if (threadIdx.x == 0) {
        float b0 = bias_init ? bias_init[row] : bias[row];
        bias[row] = b0 + acc;
    }
}

// Same math, fp32 output, for the M=10 chains. Fixed stride 2048.
__global__ void k_relu_small(const float* __restrict__ Min, float* __restrict__ Mout,
                             const float* __restrict__ wl, const float* __restrict__ wh,
                             const float* __restrict__ bhr, const float* __restrict__ bj,
                             float* __restrict__ bias, const float* __restrict__ bias_init,
                             int is_high) {
    int row = blockIdx.x;
    const float* Mr = Min + (size_t)row * 2048;
    float acc = 0.f;
    for (int c = threadIdx.x; c < 2048; c += 256) {
        float m = Mr[c];
        float out, bt;
        if (is_high) { out = (m > 0.f) ? m * wh[c] : m * wl[c]; bt = fmaxf(m, 0.f) * bhr[c]; }
        else         { out = (m > 0.f) ? m * wl[c] : m * wh[c]; bt = fminf(m, 0.f) * bhr[c]; }
        acc += bt + out * bj[c];
        Mout[(size_t)row * 2048 + c] = out;
    }
    acc = blockReduce256(acc);
    if (threadIdx.x == 0) {
        float b0 = bias_init ? bias_init[row] : bias[row];
        bias[row] = b0 + acc;
    }
}

// Transpose + bf16 hi/lo split: Wt[n][k] = W[k][n]; pad n in [NC,NP) with 0.
__global__ void k_transpose_split(const float* __restrict__ W, int NC,
                                  __hip_bfloat16* __restrict__ Thi,
                                  __hip_bfloat16* __restrict__ Tlo) {
    __shared__ float s[32][33];
    int c = threadIdx.x & 31;
    int r = threadIdx.x >> 5;  // 0..7
    #pragma unroll
    for (int rr = 0; rr < 4; rr++) {
        int k = blockIdx.y * 32 + r + rr * 8;
        int n = blockIdx.x * 32 + c;
        float v = (n < NC) ? W[(size_t)k * NC + n] : 0.f;
        s[c][r + rr * 8] = v;  // s[n_local][k_local]
    }
    __syncthreads();
    #pragma unroll
    for (int rr = 0; rr < 4; rr++) {
        int nl = r + rr * 8;
        float v = s[nl][c];
        __hip_bfloat16 h = __float2bfloat16(v);
        size_t o = (size_t)(blockIdx.x * 32 + nl) * 2048 + blockIdx.y * 32 + c;
        Thi[o] = h;
        Tlo[o] = __float2bfloat16(v - __bfloat162float(h));
    }
}

// C[2048,Npad] = (Ahi+Alo)[2048,2048] @ (Bt hi/lo [Npad,2048])^T, 3 bf16 products.
// BM=128 BN=64 BK=32, 256 threads (4 waves, 2x2 wave grid; wave tile 64x32).
__global__ __launch_bounds__(256, 2) void k_gemm_mfma(
        const __hip_bfloat16* __restrict__ Ahi, const __hip_bfloat16* __restrict__ Alo,
        const __hip_bfloat16* __restrict__ Bhi, const __hip_bfloat16* __restrict__ Blo,
        float* __restrict__ C, int ldc) {
    __shared__ unsigned short sAhi[128 * 32], sAlo[128 * 32];
    __shared__ unsigned short sBhi[64 * 32],  sBlo[64 * 32];
    int tid = threadIdx.x;
    int row0 = blockIdx.y * 128, col0 = blockIdx.x * 64;

    // staging addresses: LDS element offset == tid*8 (+2048 for A pass 2)
    int sr = tid >> 2;               // 0..63
    int sc = (tid & 3) * 8;
    const unsigned short* gAh0 = (const unsigned short*)Ahi + (size_t)(row0 + sr) * 2048 + sc;
    const unsigned short* gAl0 = (const unsigned short*)Alo + (size_t)(row0 + sr) * 2048 + sc;
    const unsigned short* gAh1 = gAh0 + (size_t)64 * 2048;
    const unsigned short* gAl1 = gAl0 + (size_t)64 * 2048;
    const unsigned short* gBh  = (const unsigned short*)Bhi + (size_t)(col0 + sr) * 2048 + sc;
    const unsigned short* gBl  = (const unsigned short*)Blo + (size_t)(col0 + sr) * 2048 + sc;
    unsigned short* lAh0 = &sAhi[tid * 8];
    unsigned short* lAl0 = &sAlo[tid * 8];
    unsigned short* lAh1 = &sAhi[tid * 8 + 2048];
    unsigned short* lAl1 = &sAlo[tid * 8 + 2048];
    unsigned short* lBh  = &sBhi[tid * 8];
    unsigned short* lBl  = &sBlo[tid * 8];

    int lane = tid & 63, wv = tid >> 6;
    int wm = wv & 1, wn = wv >> 1;
    int l15 = lane & 15, q = lane >> 4;
    int aoff = (wm * 64 + l15) * 32 + q * 8;   // + mt*512
    int boff = (wn * 32 + l15) * 32 + q * 8;   // + nt*512

    floatx4 acc[4][2];
    floatx4 z = {0.f, 0.f, 0.f, 0.f};
    #pragma unroll
    for (int i = 0; i < 4; i++) { acc[i][0] = z; acc[i][1] = z; }

    for (int k0 = 0; k0 < 2048; k0 += 32) {
        gl2lds16(gAh0 + k0, lAh0);
        gl2lds16(gAh1 + k0, lAh1);
        gl2lds16(gAl0 + k0, lAl0);
        gl2lds16(gAl1 + k0, lAl1);
        gl2lds16(gBh + k0, lBh);
        gl2lds16(gBl + k0, lBl);
        __syncthreads();
        bf16x8 bh0 = *(const bf16x8*)&sBhi[boff];
        bf16x8 bh1 = *(const bf16x8*)&sBhi[boff + 512];
        bf16x8 bl0 = *(const bf16x8*)&sBlo[boff];
        bf16x8 bl1 = *(const bf16x8*)&sBlo[boff + 512];
        #pragma unroll
        for (int mt = 0; mt < 4; mt++) {
            bf16x8 ah = *(const bf16x8*)&sAhi[aoff + mt * 512];
            bf16x8 al = *(const bf16x8*)&sAlo[aoff + mt * 512];
            acc[mt][0] = __builtin_amdgcn_mfma_f32_16x16x32_bf16(ah, bh0, acc[mt][0], 0, 0, 0);
            acc[mt][0] = __builtin_amdgcn_mfma_f32_16x16x32_bf16(al, bh0, acc[mt][0], 0, 0, 0);
            acc[mt][0] = __builtin_amdgcn_mfma_f32_16x16x32_bf16(ah, bl0, acc[mt][0], 0, 0, 0);
            acc[mt][1] = __builtin_amdgcn_mfma_f32_16x16x32_bf16(ah, bh1, acc[mt][1], 0, 0, 0);
            acc[mt][1] = __builtin_amdgcn_mfma_f32_16x16x32_bf16(al, bh1, acc[mt][1], 0, 0, 0);
            acc[mt][1] = __builtin_amdgcn_mfma_f32_16x16x32_bf16(ah, bl1, acc[mt][1], 0, 0, 0);
        }
        __syncthreads();
    }
    // C/D layout: col = lane&15, row = (lane>>4)*4 + reg
    #pragma unroll
    for (int mt = 0; mt < 4; mt++) {
        int gr = row0 + wm * 64 + mt * 16 + q * 4;
        #pragma unroll
        for (int nt = 0; nt < 2; nt++) {
            int gc = col0 + wn * 32 + nt * 16 + l15;
            #pragma unroll
            for (int r = 0; r < 4; r++)
                C[(size_t)(gr + r) * ldc + gc] = acc[mt][nt][r];
        }
    }
}

// Skinny fp32: Cout[10,N] += A[10,2048] @ W[2048,N], split-K over grid.y (8).
__global__ __launch_bounds__(256) void k_skinny(const float* __restrict__ A,
                                                const float* __restrict__ W, int N,
                                                float* __restrict__ Cout) {
    __shared__ float sA[10][256];
    int k0 = blockIdx.y * 256;
    int tid = threadIdx.x;
    for (int idx = tid; idx < 10 * 256; idx += 256) {
        int r = idx >> 8, k = idx & 255;
        sA[r][k] = A[(size_t)r * 2048 + k0 + k];
    }
    __syncthreads();
    int c = blockIdx.x * 128 + (tid & 127);
    int kh = tid >> 7;
    if (c < N) {
        float acc[10];
        #pragma unroll
        for (int r = 0; r < 10; r++) acc[r] = 0.f;
        const float* Wp = W + (size_t)(k0 + kh * 128) * N + c;
        for (int kk = 0; kk < 128; kk++) {
            float w = Wp[(size_t)kk * N];
            #pragma unroll
            for (int r = 0; r < 10; r++) acc[r] += sA[r][kh * 128 + kk] * w;
        }
        #pragma unroll
        for (int r = 0; r < 10; r++) atomicAdd(&Cout[(size_t)r * N + c], acc[r]);
    }
}

__global__ void k_fboxes(const float* __restrict__ M, int lda, int cols,
                         const float* __restrict__ bias,
                         const float* __restrict__ lo0, const float* __restrict__ hi0,
                         float* __restrict__ out, int is_high) {
    int r = blockIdx.x;
    const float* Mr = M + (size_t)r * lda;
    float acc = 0.f;
    for (int c = threadIdx.x; c < cols; c += 256) {
        float m = Mr[c];
        if (is_high) acc += (m < 0.f) ? m * lo0[c] : m * hi0[c];
        else         acc += (m < 0.f) ? m * hi0[c] : m * lo0[c];
    }
    acc = blockReduce256(acc);
    if (threadIdx.x == 0) out[r] = acc + bias[r];
}

__global__ void k_relu_rec(float* __restrict__ x, const float* __restrict__ lo,
                           const float* __restrict__ hi, float* __restrict__ wl,
                           float* __restrict__ wh, float* __restrict__ bhr, int n) {
    int i = blockIdx.x * blockDim.x + threadIdx.x;
    if (i < n) {
        float l = lo[i], h = hi[i];
        float vwl, vwh, vbh;
        if (h <= 0.f)      { vwl = 0.f; vwh = 0.f; vbh = 0.f; }
        else if (l >= 0.f) { vwl = 1.f; vwh = 1.f; vbh = 0.f; }
        else {
            float d = h - l;
            vwh = h / d;
            vbh = -(l * h) / d;
            vwl = (l * l > h * h) ? 0.f : 1.f;
        }
        wl[i] = vwl; wh[i] = vwh; bhr[i] = vbh;
        x[i] = fmaxf(x[i], 0.f);
    }
}

extern "C" void kernel_launch(void* const* d_in, const int* in_sizes, int n_in,
                              void* d_out, int out_size, void* d_ws, size_t ws_size,
                              hipStream_t stream) {
    const float* x_in  = (const float*)d_in[0];
    const float* lo_in = (const float*)d_in[1];
    const float* hi_in = (const float*)d_in[2];
    const float* W[5];
    const float* bv[5];
    for (int i = 0; i < 5; i++) {
        W[i]  = (const float*)d_in[3 + 2 * i];
        bv[i] = (const float*)d_in[4 + 2 * i];
    }
    float* ws = (float*)d_ws;
    float* out = (float*)d_out;

    float* X[2]  = {ws + OFF_X0, ws + OFF_X1};
    float* lo0   = ws + OFF_L0;
    float* hi0   = ws + OFF_H0;
    float* bias  = ws + OFF_BIAS;
    float* Cbuf  = ws + OFF_C;
    float* P0    = ws + OFF_P0;
    float* P1    = ws + OFF_P1;
    __hip_bfloat16* Ahi  = (__hip_bfloat16*)(ws + OFF_AHI);
    __hip_bfloat16* Alo  = (__hip_bfloat16*)(ws + OFF_ALO);
    __hip_bfloat16* Wthi = (__hip_bfloat16*)(ws + OFF_WTHI);
    __hip_bfloat16* Wtlo = (__hip_bfloat16*)(ws + OFF_WTLO);

    k_norm<<<4, 256, 0, stream>>>(x_in, lo_in, hi_in, ws);

    // ---- layer 0 ----
    k_matvec<<<2048, 256, 0, stream>>>(W[0], X[0], bv[0], X[1], 784);
    k_fboxes<<<2048, 256, 0, stream>>>(W[0], 784, 784, bv[0], lo0, hi0, ws + OFF_HIGHI, 1);
    k_fboxes<<<2048, 256, 0, stream>>>(W[0], 784, 784, bv[0], lo0, hi0, ws + OFF_LOWI, 0);
    k_relu_rec<<<8, 256, 0, stream>>>(X[1], ws + OFF_LOWI, ws + OFF_HIGHI,
                                      ws + OFF_WL, ws + OFF_WH, ws + OFF_BHR, 2048);

    // ---- layers 1..3 (big MFMA chains) ----
    int cur = 1;  // X[cur] holds current activation
    for (int i = 1; i <= 3; i++) {
        int nxt = cur ^ 1;
        k_matvec<<<2048, 256, 0, stream>>>(W[i], X[cur], bv[i], X[nxt], 2048);
        for (int chain = 0; chain < 2; chain++) {
            int is_high = (chain == 0) ? 1 : 0;
            const float* Min = W[i];
            for (int j = i - 1; j >= 0; j--) {
                k_relu_split<<<2048, 256, 0, stream>>>(
                    Min, 2048,
                    ws + OFF_WL + j * 2048, ws + OFF_WH + j * 2048,
                    ws + OFF_BHR + j * 2048, bv[j],
                    bias, (j == i - 1) ? bv[i] : nullptr,
                    Ahi, Alo, is_high);
                int NC = (j == 0) ? 784 : 2048;
                int NP = (j == 0) ? 896 : 2048;
                k_transpose_split<<<dim3(NP / 32, 64), 256, 0, stream>>>(W[j], NC, Wthi, Wtlo);
                k_gemm_mfma<<<dim3(NP / 64, 16), 256, 0, stream>>>(Ahi, Alo, Wthi, Wtlo, Cbuf, NP);
                Min = Cbuf;
            }
            float* dest = ws + (is_high ? OFF_HIGHI : OFF_LOWI);
            k_fboxes<<<2048, 256, 0, stream>>>(Cbuf, 896, 784, bias, lo0, hi0, dest, is_high);
        }
        k_relu_rec<<<8, 256, 0, stream>>>(X[nxt], ws + OFF_LOWI, ws + OFF_HIGHI,
                                          ws + OFF_WL + i * 2048, ws + OFF_WH + i * 2048,
                                          ws + OFF_BHR + i * 2048, 2048);
        cur = nxt;
    }

    // ---- layer 4 (M=10 chains, fp32 skinny path) ----
    k_matvec<<<10, 256, 0, stream>>>(W[4], X[cur], bv[4], out, 2048);
    for (int chain = 0; chain < 2; chain++) {
        int is_high = (chain == 0) ? 1 : 0;
        // j=3
        k_relu_small<<<10, 256, 0, stream>>>(W[4], P0,
            ws + OFF_WL + 3 * 2048, ws + OFF_WH + 3 * 2048, ws + OFF_BHR + 3 * 2048,
            bv[3], bias, bv[4], is_high);
        hipMemsetAsync(P1, 0, 10 * 2048 * sizeof(float), stream);
        k_skinny<<<dim3(16, 8), 256, 0, stream>>>(P0, W[3], 2048, P1);
        // j=2
        k_relu_small<<<10, 256, 0, stream>>>(P1, P0,
            ws + OFF_WL + 2 * 2048, ws + OFF_WH + 2 * 2048, ws + OFF_BHR + 2 * 2048,
            bv[2], bias, nullptr, is_high);
        hipMemsetAsync(P1, 0, 10 * 2048 * sizeof(float), stream);
        k_skinny<<<dim3(16, 8), 256, 0, stream>>>(P0, W[2], 2048, P1);
        // j=1
        k_relu_small<<<10, 256, 0, stream>>>(P1, P0,
            ws + OFF_WL + 1 * 2048, ws + OFF_WH + 1 * 2048, ws + OFF_BHR + 1 * 2048,
            bv[1], bias, nullptr, is_high);
        hipMemsetAsync(P1, 0, 10 * 2048 * sizeof(float), stream);
        k_skinny<<<dim3(16, 8), 256, 0, stream>>>(P0, W[1], 2048, P1);
        // j=0
        k_relu_small<<<10, 256, 0, stream>>>(P1, P0,
            ws + OFF_WL + 0 * 2048, ws + OFF_WH + 0 * 2048, ws + OFF_BHR + 0 * 2048,
            bv[0], bias, nullptr, is_high);
        hipMemsetAsync(P1, 0, 10 * 784 * sizeof(float), stream);
        k_skinny<<<dim3(7, 8), 256, 0, stream>>>(P0, W[0], 784, P1);
        k_fboxes<<<10, 256, 0, stream>>>(P1, 784, 784, bias, lo0, hi0,
                                         out + (is_high ? 20 : 10), is_high);
    }
}

// Round 3
// 1047.248 us; speedup vs baseline: 5.3748x; 1.5012x over previous
//
#include <hip/hip_runtime.h>
#include <hip/hip_bf16.h>

// DeepPoly MLP verifier (784->2048x4->10).
// Round 3: high+low chains stacked into M=4096 GEMMs; 128x128 block tile,
// 64x64 wave tile (48 MFMA : 16 ds_read_b128 per wave K-step); XOR bank
// swizzle on LDS tiles (applied at global-fetch so global_load_lds's
// uniform-base+lane*16 layout is preserved). bf16 hi/lo 3-product GEMM.

#define MEAN_C 0.1307f
#define STD_C  0.3081f

// ---- workspace offsets (floats) ----
#define OFF_X0     0u
#define OFF_X1     2048u
#define OFF_L0     4096u
#define OFF_H0     5120u
#define OFF_WL     6144u       // 4*2048
#define OFF_WH     14336u
#define OFF_BHR    22528u
#define OFF_LOWI   30720u
#define OFF_HIGHI  32768u
#define OFF_BIAS   34816u      // 4096 (high rows 0..2047, low 2048..4095)
#define OFF_P0     38912u      // 20*2048
#define OFF_P1     79872u
#define OFF_C      122880u     // fp32 [4096, <=2048] = 8388608 floats
#define OFF_AHI    8511488u    // bf16 [4096,2048] = 4194304 float-slots
#define OFF_ALO    12705792u
#define OFF_WTHI   16900096u   // bf16 [<=2048,2048] = 2097152 float-slots
#define OFF_WTLO   18997248u
// total 21094400 floats ~= 80.5 MB

typedef __bf16 bf16x8 __attribute__((ext_vector_type(8)));
typedef float floatx4 __attribute__((ext_vector_type(4)));

__device__ __forceinline__ void gl2lds16(const void* g, void* l) {
    __builtin_amdgcn_global_load_lds(
        (const __attribute__((address_space(1))) unsigned int*)g,
        (__attribute__((address_space(3))) unsigned int*)l, 16, 0, 0);
}

__device__ __forceinline__ float blockReduce256(float v) {
    #pragma unroll
    for (int o = 32; o > 0; o >>= 1) v += __shfl_down(v, o, 64);
    __shared__ float sred[4];
    int w = threadIdx.x >> 6;
    if ((threadIdx.x & 63) == 0) sred[w] = v;
    __syncthreads();
    float r = 0.f;
    if (threadIdx.x == 0) r = sred[0] + sred[1] + sred[2] + sred[3];
    return r;  // valid in thread 0 only
}

__global__ void k_norm(const float* __restrict__ x, const float* __restrict__ lo,
                       const float* __restrict__ hi, float* __restrict__ ws) {
    int i = blockIdx.x * blockDim.x + threadIdx.x;
    if (i < 784) {
        ws[OFF_X0 + i] = (x[i]  - MEAN_C) / STD_C;
        ws[OFF_L0 + i] = (lo[i] - MEAN_C) / STD_C;
        ws[OFF_H0 + i] = (hi[i] - MEAN_C) / STD_C;
    }
}

__global__ void k_matvec(const float* __restrict__ W, const float* __restrict__ x,
                         const float* __restrict__ b, float* __restrict__ y, int k) {
    int r = blockIdx.x;
    const float* Wr = W + (size_t)r * k;
    float acc = 0.f;
    for (int c = threadIdx.x; c < k; c += 256) acc += Wr[c] * x[c];
    acc = blockReduce256(acc);
    if (threadIdx.x == 0) y[r] = acc + b[r];
}

// Stacked relu-backsub: 4096 rows (0..2047 high chain, 2048..4095 low chain).
// Reads fp32 M (broadcast from [2048,lda] if bcast), applies relu_j transform,
// accumulates bias (bhr dot + b_j dot), emits bf16 hi/lo A for the GEMM.
__global__ __launch_bounds__(256) void k_relu_split(
        const float* __restrict__ Min, int lda, int bcast,
        const float* __restrict__ wl, const float* __restrict__ wh,
        const float* __restrict__ bhr, const float* __restrict__ bj,
        float* __restrict__ bias, const float* __restrict__ bias_init,
        unsigned short* __restrict__ Ahi, unsigned short* __restrict__ Alo) {
    int row = blockIdx.x;
    int is_high = row < 2048;
    int srow = bcast ? (row & 2047) : row;
    const float* src = Min + (size_t)srow * lda;
    int c0 = threadIdx.x * 8;
    float mv[8], awl[8], awh[8], ab[8], abj[8];
    *(float4*)&mv[0] = *(const float4*)(src + c0);
    *(float4*)&mv[4] = *(const float4*)(src + c0 + 4);
    *(float4*)&awl[0] = *(const float4*)(wl + c0);
    *(float4*)&awl[4] = *(const float4*)(wl + c0 + 4);
    *(float4*)&awh[0] = *(const float4*)(wh + c0);
    *(float4*)&awh[4] = *(const float4*)(wh + c0 + 4);
    *(float4*)&ab[0]  = *(const float4*)(bhr + c0);
    *(float4*)&ab[4]  = *(const float4*)(bhr + c0 + 4);
    *(float4*)&abj[0] = *(const float4*)(bj + c0);
    *(float4*)&abj[4] = *(const float4*)(bj + c0 + 4);
    float acc = 0.f;
    bf16x8 hi, lo;
    #pragma unroll
    for (int e = 0; e < 8; e++) {
        float m = mv[e];
        float t, bt;
        if (is_high) { t = (m > 0.f) ? m * awh[e] : m * awl[e]; bt = fmaxf(m, 0.f) * ab[e]; }
        else         { t = (m > 0.f) ? m * awl[e] : m * awh[e]; bt = fminf(m, 0.f) * ab[e]; }
        acc += bt + t * abj[e];
        __bf16 h = (__bf16)t;
        hi[e] = h;
        lo[e] = (__bf16)(t - (float)h);
    }
    *(bf16x8*)(Ahi + (size_t)row * 2048 + c0) = hi;
    *(bf16x8*)(Alo + (size_t)row * 2048 + c0) = lo;
    acc = blockReduce256(acc);
    if (threadIdx.x == 0) {
        float b0 = bias_init ? bias_init[srow] : bias[row];
        bias[row] = b0 + acc;
    }
}

// Transpose + bf16 hi/lo split: Wt[n][k] = W[k][n]; pad n in [NC,NP) with 0.
__global__ void k_transpose_split(const float* __restrict__ W, int NC,
                                  __hip_bfloat16* __restrict__ Thi,
                                  __hip_bfloat16* __restrict__ Tlo) {
    __shared__ float s[32][33];
    int c = threadIdx.x & 31;
    int r = threadIdx.x >> 5;  // 0..7
    #pragma unroll
    for (int rr = 0; rr < 4; rr++) {
        int k = blockIdx.y * 32 + r + rr * 8;
        int n = blockIdx.x * 32 + c;
        float v = (n < NC) ? W[(size_t)k * NC + n] : 0.f;
        s[c][r + rr * 8] = v;
    }
    __syncthreads();
    #pragma unroll
    for (int rr = 0; rr < 4; rr++) {
        int nl = r + rr * 8;
        float v = s[nl][c];
        __hip_bfloat16 h = __float2bfloat16(v);
        size_t o = (size_t)(blockIdx.x * 32 + nl) * 2048 + blockIdx.y * 32 + c;
        Thi[o] = h;
        Tlo[o] = __float2bfloat16(v - __bfloat162float(h));
    }
}

// C[4096,NP] = (Ahi+Alo)[4096,2048] @ (Bt hi/lo [NP,2048])^T, 3 bf16 products.
// BM=128, BN=NT*32, BK=32; 256 threads, 2x2 wave grid, wave tile 64x(NT*16).
// LDS XOR swizzle: data for (row, q) lives at slot q^(row&3).
template<int NT>
__global__ __launch_bounds__(256, 2) void k_gemm_mfma(
        const unsigned short* __restrict__ Ahi, const unsigned short* __restrict__ Alo,
        const unsigned short* __restrict__ Bhi, const unsigned short* __restrict__ Blo,
        float* __restrict__ C, int ldc) {
    __shared__ unsigned short sAh[128 * 32], sAl[128 * 32];
    __shared__ unsigned short sBh[NT * 32 * 32], sBl[NT * 32 * 32];
    int tid = threadIdx.x;
    int row0 = blockIdx.y * 128, col0 = blockIdx.x * (NT * 32);

    // staging: chunk c -> lds 16B slot c; row=c>>2, slot=c&3, global q=slot^(row&3)
    int cr = tid >> 2;
    int q  = (tid & 3) ^ (cr & 3);
    const unsigned short* gAh0 = Ahi + (size_t)(row0 + cr) * 2048 + q * 8;
    const unsigned short* gAl0 = Alo + (size_t)(row0 + cr) * 2048 + q * 8;
    const unsigned short* gAh1 = gAh0 + (size_t)64 * 2048;
    const unsigned short* gAl1 = gAl0 + (size_t)64 * 2048;
    const unsigned short* gBh0 = Bhi + (size_t)(col0 + cr) * 2048 + q * 8;
    const unsigned short* gBl0 = Blo + (size_t)(col0 + cr) * 2048 + q * 8;
    const unsigned short* gBh1 = gBh0 + (size_t)64 * 2048;
    const unsigned short* gBl1 = gBl0 + (size_t)64 * 2048;
    unsigned short* lAh0 = &sAh[tid * 8];
    unsigned short* lAh1 = &sAh[tid * 8 + 2048];
    unsigned short* lAl0 = &sAl[tid * 8];
    unsigned short* lAl1 = &sAl[tid * 8 + 2048];
    unsigned short* lBh0 = &sBh[tid * 8];
    unsigned short* lBl0 = &sBl[tid * 8];
    unsigned short* lBh1 = &sBh[tid * 8 + 2048];  // used only if NT==4
    unsigned short* lBl1 = &sBl[tid * 8 + 2048];

    int lane = tid & 63, wv = tid >> 6;
    int wm = wv & 1, wn = wv >> 1;
    int l15 = lane & 15, lq = lane >> 4;
    int soff = ((lq ^ (l15 & 3)) * 8);
    int arow = wm * 64 + l15;
    int brow = wn * (NT * 16) + l15;

    floatx4 acc[4][NT];
    floatx4 z = {0.f, 0.f, 0.f, 0.f};
    #pragma unroll
    for (int i = 0; i < 4; i++)
        #pragma unroll
        for (int j = 0; j < NT; j++) acc[i][j] = z;

    for (int k0 = 0; k0 < 2048; k0 += 32) {
        gl2lds16(gAh0 + k0, lAh0);
        gl2lds16(gAh1 + k0, lAh1);
        gl2lds16(gAl0 + k0, lAl0);
        gl2lds16(gAl1 + k0, lAl1);
        gl2lds16(gBh0 + k0, lBh0);
        gl2lds16(gBl0 + k0, lBl0);
        if (NT == 4) {
            gl2lds16(gBh1 + k0, lBh1);
            gl2lds16(gBl1 + k0, lBl1);
        }
        __syncthreads();
        bf16x8 bh[NT], bl[NT];
        #pragma unroll
        for (int nt = 0; nt < NT; nt++) {
            bh[nt] = *(const bf16x8*)&sBh[(brow + nt * 16) * 32 + soff];
            bl[nt] = *(const bf16x8*)&sBl[(brow + nt * 16) * 32 + soff];
        }
        #pragma unroll
        for (int mt = 0; mt < 4; mt++) {
            bf16x8 ah = *(const bf16x8*)&sAh[(arow + mt * 16) * 32 + soff];
            bf16x8 al = *(const bf16x8*)&sAl[(arow + mt * 16) * 32 + soff];
            #pragma unroll
            for (int nt = 0; nt < NT; nt++) {
                acc[mt][nt] = __builtin_amdgcn_mfma_f32_16x16x32_bf16(ah, bh[nt], acc[mt][nt], 0, 0, 0);
                acc[mt][nt] = __builtin_amdgcn_mfma_f32_16x16x32_bf16(al, bh[nt], acc[mt][nt], 0, 0, 0);
                acc[mt][nt] = __builtin_amdgcn_mfma_f32_16x16x32_bf16(ah, bl[nt], acc[mt][nt], 0, 0, 0);
            }
        }
        __syncthreads();
    }
    // C/D layout: col = lane&15, row = (lane>>4)*4 + reg
    #pragma unroll
    for (int mt = 0; mt < 4; mt++) {
        int gr = row0 + wm * 64 + mt * 16 + lq * 4;
        #pragma unroll
        for (int nt = 0; nt < NT; nt++) {
            int gc = col0 + wn * (NT * 16) + nt * 16 + l15;
            #pragma unroll
            for (int r = 0; r < 4; r++)
                C[(size_t)(gr + r) * ldc + gc] = acc[mt][nt][r];
        }
    }
}

// Skinny fp32 (layer-5 chains, 20 rows): Cout[20,N] += A[20,2048] @ W[2048,N].
__global__ __launch_bounds__(256) void k_skinny(const float* __restrict__ A,
                                                const float* __restrict__ W, int N,
                                                float* __restrict__ Cout) {
    __shared__ float sA[20][256];
    int k0 = blockIdx.y * 256;
    int tid = threadIdx.x;
    for (int idx = tid; idx < 20 * 256; idx += 256) {
        int r = idx >> 8, k = idx & 255;
        sA[r][k] = A[(size_t)r * 2048 + k0 + k];
    }
    __syncthreads();
    int c = blockIdx.x * 128 + (tid & 127);
    int kh = tid >> 7;
    if (c < N) {
        float acc[20];
        #pragma unroll
        for (int r = 0; r < 20; r++) acc[r] = 0.f;
        const float* Wp = W + (size_t)(k0 + kh * 128) * N + c;
        for (int kk = 0; kk < 128; kk++) {
            float w = Wp[(size_t)kk * N];
            #pragma unroll
            for (int r = 0; r < 20; r++) acc[r] += sA[r][kh * 128 + kk] * w;
        }
        #pragma unroll
        for (int r = 0; r < 20; r++) atomicAdd(&Cout[(size_t)r * N + c], acc[r]);
    }
}

// relu-backsub for the 20-row layer-5 chains (rows 0..9 high, 10..19 low).
__global__ void k_relu_small(const float* __restrict__ Min, int bcast,
                             float* __restrict__ Mout,
                             const float* __restrict__ wl, const float* __restrict__ wh,
                             const float* __restrict__ bhr, const float* __restrict__ bj,
                             float* __restrict__ bias, const float* __restrict__ bias_init,
                             int is_high_thresh) {
    int row = blockIdx.x;
    int is_high = row < is_high_thresh;
    int srow = bcast ? (row >= is_high_thresh ? row - is_high_thresh : row) : row;
    const float* Mr = Min + (size_t)srow * 2048;
    float acc = 0.f;
    for (int c = threadIdx.x; c < 2048; c += 256) {
        float m = Mr[c];
        float out, bt;
        if (is_high) { out = (m > 0.f) ? m * wh[c] : m * wl[c]; bt = fmaxf(m, 0.f) * bhr[c]; }
        else         { out = (m > 0.f) ? m * wl[c] : m * wh[c]; bt = fminf(m, 0.f) * bhr[c]; }
        acc += bt + out * bj[c];
        Mout[(size_t)row * 2048 + c] = out;
    }
    acc = blockReduce256(acc);
    if (threadIdx.x == 0) {
        float b0 = bias_init ? bias_init[srow] : bias[row];
        bias[row] = b0 + acc;
    }
}

__global__ void k_fboxes(const float* __restrict__ M, int lda, int cols,
                         const float* __restrict__ bias,
                         const float* __restrict__ lo0, const float* __restrict__ hi0,
                         float* __restrict__ out, int is_high) {
    int r = blockIdx.x;
    const float* Mr = M + (size_t)r * lda;
    float acc = 0.f;
    for (int c = threadIdx.x; c < cols; c += 256) {
        float m = Mr[c];
        if (is_high) acc += (m < 0.f) ? m * lo0[c] : m * hi0[c];
        else         acc += (m < 0.f) ? m * hi0[c] : m * lo0[c];
    }
    acc = blockReduce256(acc);
    if (threadIdx.x == 0) out[r] = acc + bias[r];
}

__global__ void k_relu_rec(float* __restrict__ x, const float* __restrict__ lo,
                           const float* __restrict__ hi, float* __restrict__ wl,
                           float* __restrict__ wh, float* __restrict__ bhr, int n) {
    int i = blockIdx.x * blockDim.x + threadIdx.x;
    if (i < n) {
        float l = lo[i], h = hi[i];
        float vwl, vwh, vbh;
        if (h <= 0.f)      { vwl = 0.f; vwh = 0.f; vbh = 0.f; }
        else if (l >= 0.f) { vwl = 1.f; vwh = 1.f; vbh = 0.f; }
        else {
            float d = h - l;
            vwh = h / d;
            vbh = -(l * h) / d;
            vwl = (l * l > h * h) ? 0.f : 1.f;
        }
        wl[i] = vwl; wh[i] = vwh; bhr[i] = vbh;
        x[i] = fmaxf(x[i], 0.f);
    }
}

extern "C" void kernel_launch(void* const* d_in, const int* in_sizes, int n_in,
                              void* d_out, int out_size, void* d_ws, size_t ws_size,
                              hipStream_t stream) {
    const float* x_in  = (const float*)d_in[0];
    const float* lo_in = (const float*)d_in[1];
    const float* hi_in = (const float*)d_in[2];
    const float* W[5];
    const float* bv[5];
    for (int i = 0; i < 5; i++) {
        W[i]  = (const float*)d_in[3 + 2 * i];
        bv[i] = (const float*)d_in[4 + 2 * i];
    }
    float* ws = (float*)d_ws;
    float* out = (float*)d_out;

    float* X[2]  = {ws + OFF_X0, ws + OFF_X1};
    float* lo0   = ws + OFF_L0;
    float* hi0   = ws + OFF_H0;
    float* bias  = ws + OFF_BIAS;
    float* Cbuf  = ws + OFF_C;
    float* P0    = ws + OFF_P0;
    float* P1    = ws + OFF_P1;
    unsigned short* Ahi = (unsigned short*)(ws + OFF_AHI);
    unsigned short* Alo = (unsigned short*)(ws + OFF_ALO);
    __hip_bfloat16* Wthi = (__hip_bfloat16*)(ws + OFF_WTHI);
    __hip_bfloat16* Wtlo = (__hip_bfloat16*)(ws + OFF_WTLO);

    k_norm<<<4, 256, 0, stream>>>(x_in, lo_in, hi_in, ws);

    // ---- layer 0 ----
    k_matvec<<<2048, 256, 0, stream>>>(W[0], X[0], bv[0], X[1], 784);
    k_fboxes<<<2048, 256, 0, stream>>>(W[0], 784, 784, bv[0], lo0, hi0, ws + OFF_HIGHI, 1);
    k_fboxes<<<2048, 256, 0, stream>>>(W[0], 784, 784, bv[0], lo0, hi0, ws + OFF_LOWI, 0);
    k_relu_rec<<<8, 256, 0, stream>>>(X[1], ws + OFF_LOWI, ws + OFF_HIGHI,
                                      ws + OFF_WL, ws + OFF_WH, ws + OFF_BHR, 2048);

    // ---- layers 1..3: stacked (high+low) MFMA chains, M=4096 ----
    int cur = 1;
    for (int i = 1; i <= 3; i++) {
        int nxt = cur ^ 1;
        k_matvec<<<2048, 256, 0, stream>>>(W[i], X[cur], bv[i], X[nxt], 2048);
        for (int j = i - 1; j >= 0; j--) {
            int first = (j == i - 1);
            // transform with record j (reads W_i broadcast if first, else Cbuf)
            k_relu_split<<<4096, 256, 0, stream>>>(
                first ? W[i] : Cbuf, 2048, first ? 1 : 0,
                ws + OFF_WL + j * 2048, ws + OFF_WH + j * 2048,
                ws + OFF_BHR + j * 2048, bv[j],
                bias, first ? bv[i] : nullptr, Ahi, Alo);
            int NC = (j == 0) ? 784 : 2048;
            int NP = (j == 0) ? 896 : 2048;
            k_transpose_split<<<dim3(NP / 32, 64), 256, 0, stream>>>(W[j], NC, Wthi, Wtlo);
            if (j == 0) {
                k_gemm_mfma<2><<<dim3(NP / 64, 32), 256, 0, stream>>>(
                    Ahi, Alo, (const unsigned short*)Wthi, (const unsigned short*)Wtlo, Cbuf, NP);
            } else {
                k_gemm_mfma<4><<<dim3(NP / 128, 32), 256, 0, stream>>>(
                    Ahi, Alo, (const unsigned short*)Wthi, (const unsigned short*)Wtlo, Cbuf, NP);
            }
        }
        k_fboxes<<<2048, 256, 0, stream>>>(Cbuf, 896, 784, bias, lo0, hi0, ws + OFF_HIGHI, 1);
        k_fboxes<<<2048, 256, 0, stream>>>(Cbuf + (size_t)2048 * 896, 896, 784, bias + 2048,
                                           lo0, hi0, ws + OFF_LOWI, 0);
        k_relu_rec<<<8, 256, 0, stream>>>(X[nxt], ws + OFF_LOWI, ws + OFF_HIGHI,
                                          ws + OFF_WL + i * 2048, ws + OFF_WH + i * 2048,
                                          ws + OFF_BHR + i * 2048, 2048);
        cur = nxt;
    }

    // ---- layer 4 (20-row batched skinny chains) ----
    k_matvec<<<10, 256, 0, stream>>>(W[4], X[cur], bv[4], out, 2048);
    // j=3
    k_relu_small<<<20, 256, 0, stream>>>(W[4], 1, P0,
        ws + OFF_WL + 3 * 2048, ws + OFF_WH + 3 * 2048, ws + OFF_BHR + 3 * 2048,
        bv[3], bias, bv[4], 10);
    hipMemsetAsync(P1, 0, 20 * 2048 * sizeof(float), stream);
    k_skinny<<<dim3(16, 8), 256, 0, stream>>>(P0, W[3], 2048, P1);
    // j=2
    k_relu_small<<<20, 256, 0, stream>>>(P1, 0, P0,
        ws + OFF_WL + 2 * 2048, ws + OFF_WH + 2 * 2048, ws + OFF_BHR + 2 * 2048,
        bv[2], bias, nullptr, 10);
    hipMemsetAsync(P1, 0, 20 * 2048 * sizeof(float), stream);
    k_skinny<<<dim3(16, 8), 256, 0, stream>>>(P0, W[2], 2048, P1);
    // j=1
    k_relu_small<<<20, 256, 0, stream>>>(P1, 0, P0,
        ws + OFF_WL + 1 * 2048, ws + OFF_WH + 1 * 2048, ws + OFF_BHR + 1 * 2048,
        bv[1], bias, nullptr, 10);
    hipMemsetAsync(P1, 0, 20 * 2048 * sizeof(float), stream);
    k_skinny<<<dim3(16, 8), 256, 0, stream>>>(P0, W[1], 2048, P1);
    // j=0
    k_relu_small<<<20, 256, 0, stream>>>(P1, 0, P0,
        ws + OFF_WL + 0 * 2048, ws + OFF_WH + 0 * 2048, ws + OFF_BHR + 0 * 2048,
        bv[0], bias, nullptr, 10);
    hipMemsetAsync(P1, 0, 20 * 784 * sizeof(float), stream);
    k_skinny<<<dim3(7, 8), 256, 0, stream>>>(P0, W[0], 784, P1);
    k_fboxes<<<10, 256, 0, stream>>>(P1, 784, 784, bias, lo0, hi0, out + 20, 1);
    k_fboxes<<<10, 256, 0, stream>>>(P1 + (size_t)10 * 784, 784, 784, bias + 10,
                                     lo0, hi0, out + 10, 0);
}

// Round 5
// 972.740 us; speedup vs baseline: 5.7864x; 1.0766x over previous
//
#include <hip/hip_runtime.h>
#include <hip/hip_bf16.h>

// DeepPoly MLP verifier (784->2048x4->10).
// Round 5: f16 hi/lo 3-product MFMA GEMM (hh+hl+lh, ~2^-21 eff precision —
// round 4's 2-product f16 failed at absmax 1024 because B's 2^-12 error sums
// coherently under interval arithmetic). Fused epilogues kept from round 4:
// relu-backsub transform + bias atomics in GEMM epilogue (emits next A hi/lo),
// interval-matvec epilogue into bias-initialized BOX on the last step.
// Layer-4 (20-row) chains: split-K partials + reduce-in-next-prep.

#define MEAN_C 0.1307f
#define STD_C  0.3081f

// ---- workspace offsets (floats), total ~84 MB ----
#define OFF_X0     0u          // 2048
#define OFF_X1     2048u
#define OFF_L0     4096u       // 896 used (padded, zeroed to 896)
#define OFF_H0     5120u
#define OFF_WL     6144u       // 4*2048
#define OFF_WH     14336u
#define OFF_BHR    22528u
#define OFF_BOX    30720u      // 4096: [0..2047]=high, [2048..4095]=low
#define OFF_BIAS   34816u      // 4096
#define OFF_B20    38912u      // 32
// WT region (layers 1..3) unioned with PC/PP (layer 4, temporally disjoint)
#define OFF_WTH    38944u      // f16 [<=2048][2048] hi = 2097152 float-slots
#define OFF_WTL    2136096u    // f16 lo
#define OFF_PC     38944u      // 20*2048 fp32 (layer-4 only)
#define OFF_PP     79904u      // 8*20*2048 fp32 split-K partials (layer-4 only)
#define OFF_AH0    4233248u    // f16 [4096][2048] = 4194304 float-slots
#define OFF_AL0    8427552u
#define OFF_AH1    12621856u
#define OFF_AL1    16816160u
// end = 21010464 floats ~= 84.0 MB

typedef _Float16 half8 __attribute__((ext_vector_type(8)));
typedef float floatx4 __attribute__((ext_vector_type(4)));

__device__ __forceinline__ void gl2lds16(const void* g, void* l) {
    __builtin_amdgcn_global_load_lds(
        (const __attribute__((address_space(1))) unsigned int*)g,
        (__attribute__((address_space(3))) unsigned int*)l, 16, 0, 0);
}

__device__ __forceinline__ float blockReduce256(float v) {
    #pragma unroll
    for (int o = 32; o > 0; o >>= 1) v += __shfl_down(v, o, 64);
    __shared__ float sred[4];
    int w = threadIdx.x >> 6;
    if ((threadIdx.x & 63) == 0) sred[w] = v;
    __syncthreads();
    float r = 0.f;
    if (threadIdx.x == 0) r = sred[0] + sred[1] + sred[2] + sred[3];
    return r;  // valid in thread 0 only
}

__global__ void k_norm(const float* __restrict__ x, const float* __restrict__ lo,
                       const float* __restrict__ hi, float* __restrict__ ws) {
    int i = blockIdx.x * blockDim.x + threadIdx.x;
    if (i < 784) {
        ws[OFF_X0 + i] = (x[i]  - MEAN_C) / STD_C;
        ws[OFF_L0 + i] = (lo[i] - MEAN_C) / STD_C;
        ws[OFF_H0 + i] = (hi[i] - MEAN_C) / STD_C;
    } else if (i < 896) {  // zero-pad box so padded GEMM cols contribute 0
        ws[OFF_L0 + i] = 0.f;
        ws[OFF_H0 + i] = 0.f;
    }
}

__global__ void k_matvec(const float* __restrict__ W, const float* __restrict__ x,
                         const float* __restrict__ b, float* __restrict__ y, int k) {
    int r = blockIdx.x;
    const float* Wr = W + (size_t)r * k;
    float acc = 0.f;
    for (int c = threadIdx.x; c < k; c += 256) acc += Wr[c] * x[c];
    acc = blockReduce256(acc);
    if (threadIdx.x == 0) y[r] = acc + b[r];
}

// Layer-0 interval matvec: BOX[r] (r<2048 high, else low) from W0 directly.
__global__ void k_fboxes0(const float* __restrict__ W0, const float* __restrict__ b0,
                          const float* __restrict__ lo0, const float* __restrict__ hi0,
                          float* __restrict__ box) {
    int r = blockIdx.x;
    int srow = r & 2047;
    int is_high = r < 2048;
    const float* Wr = W0 + (size_t)srow * 784;
    float acc = 0.f;
    for (int c = threadIdx.x; c < 784; c += 256) {
        float m = Wr[c];
        if (is_high) acc += (m < 0.f) ? m * lo0[c] : m * hi0[c];
        else         acc += (m < 0.f) ? m * hi0[c] : m * lo0[c];
    }
    acc = blockReduce256(acc);
    if (threadIdx.x == 0) box[r] = acc + b0[srow];
}

// First backsub step for layer i: T_{i-1}(W_i) stacked (4096 rows), emits f16
// hi/lo A and initializes bias = bv_i + (bhr terms + T@b_{i-1}).
__global__ __launch_bounds__(256) void k_relu_split(
        const float* __restrict__ Min,
        const float* __restrict__ wl, const float* __restrict__ wh,
        const float* __restrict__ bhr, const float* __restrict__ bj,
        float* __restrict__ bias, const float* __restrict__ bias_init,
        _Float16* __restrict__ Ahi, _Float16* __restrict__ Alo) {
    int row = blockIdx.x;
    int is_high = row < 2048;
    int srow = row & 2047;
    const float* src = Min + (size_t)srow * 2048;
    int c0 = threadIdx.x * 8;
    float mv[8], awl[8], awh[8], ab[8], abj[8];
    *(float4*)&mv[0]  = *(const float4*)(src + c0);
    *(float4*)&mv[4]  = *(const float4*)(src + c0 + 4);
    *(float4*)&awl[0] = *(const float4*)(wl + c0);
    *(float4*)&awl[4] = *(const float4*)(wl + c0 + 4);
    *(float4*)&awh[0] = *(const float4*)(wh + c0);
    *(float4*)&awh[4] = *(const float4*)(wh + c0 + 4);
    *(float4*)&ab[0]  = *(const float4*)(bhr + c0);
    *(float4*)&ab[4]  = *(const float4*)(bhr + c0 + 4);
    *(float4*)&abj[0] = *(const float4*)(bj + c0);
    *(float4*)&abj[4] = *(const float4*)(bj + c0 + 4);
    float acc = 0.f;
    half8 hi, lo;
    #pragma unroll
    for (int e = 0; e < 8; e++) {
        float m = mv[e];
        float t, bt;
        if (is_high) { t = (m > 0.f) ? m * awh[e] : m * awl[e]; bt = fmaxf(m, 0.f) * ab[e]; }
        else         { t = (m > 0.f) ? m * awl[e] : m * awh[e]; bt = fminf(m, 0.f) * ab[e]; }
        acc += bt + t * abj[e];
        _Float16 h = (_Float16)t;
        hi[e] = h;
        lo[e] = (_Float16)(t - (float)h);
    }
    *(half8*)(Ahi + (size_t)row * 2048 + c0) = hi;
    *(half8*)(Alo + (size_t)row * 2048 + c0) = lo;
    acc = blockReduce256(acc);
    if (threadIdx.x == 0) bias[row] = bias_init[srow] + acc;
}

// Transpose + f16 hi/lo split: Wt[n][k] = W[k][n]; pad n in [NC,NP) with 0.
__global__ void k_transpose_split(const float* __restrict__ W, int NC,
                                  _Float16* __restrict__ Thi,
                                  _Float16* __restrict__ Tlo) {
    __shared__ float s[32][33];
    int c = threadIdx.x & 31;
    int r = threadIdx.x >> 5;  // 0..7
    #pragma unroll
    for (int rr = 0; rr < 4; rr++) {
        int k = blockIdx.y * 32 + r + rr * 8;
        int n = blockIdx.x * 32 + c;
        float v = (n < NC) ? W[(size_t)k * NC + n] : 0.f;
        s[c][r + rr * 8] = v;
    }
    __syncthreads();
    #pragma unroll
    for (int rr = 0; rr < 4; rr++) {
        int nl = r + rr * 8;
        float v = s[nl][c];
        _Float16 h = (_Float16)v;
        size_t o = (size_t)(blockIdx.x * 32 + nl) * 2048 + blockIdx.y * 32 + c;
        Thi[o] = h;
        Tlo[o] = (_Float16)(v - (float)h);
    }
}

__global__ void k_initbox(const float* __restrict__ bias, float* __restrict__ box) {
    int i = blockIdx.x * blockDim.x + threadIdx.x;
    box[i] = bias[i];
}

// C[4096,NP] = (Ah+Al)[4096,2048] @ (Bh+Bl)[NP,2048]^T, 3 f16 products
// (hh + lh + hl; ll dropped ~2^-22 rel).
// BM=128, BN=NT*32, BK=32; 256 threads, 2x2 waves, wave tile 64x(NT*16).
// EPI 0: relu-backsub epilogue (emit next Ah/Al + bias atomics).
// EPI 1: interval-matvec epilogue (atomics into bias-initialized BOX).
template<int NT, int EPI>
__global__ __launch_bounds__(256, 2) void k_gemm(
        const _Float16* __restrict__ Ah, const _Float16* __restrict__ Al,
        const _Float16* __restrict__ Bh, const _Float16* __restrict__ Bl,
        const float* __restrict__ wl, const float* __restrict__ wh,
        const float* __restrict__ bhr, const float* __restrict__ bj,
        float* __restrict__ bias,
        _Float16* __restrict__ oAh, _Float16* __restrict__ oAl,
        const float* __restrict__ lo0, const float* __restrict__ hi0,
        float* __restrict__ box) {
    __shared__ _Float16 sAh[128 * 32], sAl[128 * 32];
    __shared__ _Float16 sBh[NT * 32 * 32], sBl[NT * 32 * 32];
    int tid = threadIdx.x;
    int row0 = blockIdx.y * 128, col0 = blockIdx.x * (NT * 32);

    int cr = tid >> 2;
    int q  = (tid & 3) ^ (cr & 3);          // XOR bank swizzle at fetch
    const _Float16* gAh0 = Ah + (size_t)(row0 + cr) * 2048 + q * 8;
    const _Float16* gAh1 = gAh0 + (size_t)64 * 2048;
    const _Float16* gAl0 = Al + (size_t)(row0 + cr) * 2048 + q * 8;
    const _Float16* gAl1 = gAl0 + (size_t)64 * 2048;
    const _Float16* gBh0 = Bh + (size_t)(col0 + cr) * 2048 + q * 8;
    const _Float16* gBl0 = Bl + (size_t)(col0 + cr) * 2048 + q * 8;
    const _Float16* gBh1 = gBh0 + (size_t)64 * 2048;   // NT==4 only
    const _Float16* gBl1 = gBl0 + (size_t)64 * 2048;
    _Float16* lAh0 = &sAh[tid * 8];
    _Float16* lAh1 = &sAh[tid * 8 + 2048];
    _Float16* lAl0 = &sAl[tid * 8];
    _Float16* lAl1 = &sAl[tid * 8 + 2048];
    _Float16* lBh0 = &sBh[tid * 8];
    _Float16* lBl0 = &sBl[tid * 8];
    _Float16* lBh1 = &sBh[tid * 8 + 2048];
    _Float16* lBl1 = &sBl[tid * 8 + 2048];

    int lane = tid & 63, wv = tid >> 6;
    int wm = wv & 1, wn = wv >> 1;
    int l15 = lane & 15, lq = lane >> 4;
    int soff = (lq ^ (l15 & 3)) * 8;
    int arow = wm * 64 + l15;
    int brow = wn * (NT * 16) + l15;

    floatx4 acc[4][NT];
    floatx4 z = {0.f, 0.f, 0.f, 0.f};
    #pragma unroll
    for (int i = 0; i < 4; i++)
        #pragma unroll
        for (int j = 0; j < NT; j++) acc[i][j] = z;

    for (int k0 = 0; k0 < 2048; k0 += 32) {
        gl2lds16(gAh0 + k0, lAh0);
        gl2lds16(gAh1 + k0, lAh1);
        gl2lds16(gAl0 + k0, lAl0);
        gl2lds16(gAl1 + k0, lAl1);
        gl2lds16(gBh0 + k0, lBh0);
        gl2lds16(gBl0 + k0, lBl0);
        if (NT == 4) {
            gl2lds16(gBh1 + k0, lBh1);
            gl2lds16(gBl1 + k0, lBl1);
        }
        __syncthreads();
        half8 bh[NT], bl[NT];
        #pragma unroll
        for (int nt = 0; nt < NT; nt++) {
            bh[nt] = *(const half8*)&sBh[(brow + nt * 16) * 32 + soff];
            bl[nt] = *(const half8*)&sBl[(brow + nt * 16) * 32 + soff];
        }
        #pragma unroll
        for (int mt = 0; mt < 4; mt++) {
            half8 ah = *(const half8*)&sAh[(arow + mt * 16) * 32 + soff];
            half8 al = *(const half8*)&sAl[(arow + mt * 16) * 32 + soff];
            #pragma unroll
            for (int nt = 0; nt < NT; nt++) {
                acc[mt][nt] = __builtin_amdgcn_mfma_f32_16x16x32_f16(ah, bh[nt], acc[mt][nt], 0, 0, 0);
                acc[mt][nt] = __builtin_amdgcn_mfma_f32_16x16x32_f16(al, bh[nt], acc[mt][nt], 0, 0, 0);
                acc[mt][nt] = __builtin_amdgcn_mfma_f32_16x16x32_f16(ah, bl[nt], acc[mt][nt], 0, 0, 0);
            }
        }
        __syncthreads();
    }

    // C/D layout: col = lane&15, row = (lane>>4)*4 + reg
    int is_high = row0 < 2048;  // uniform per block (BM=128 divides 2048)
    float bsum[4][4];
    #pragma unroll
    for (int mt = 0; mt < 4; mt++)
        #pragma unroll
        for (int r = 0; r < 4; r++) bsum[mt][r] = 0.f;

    #pragma unroll
    for (int nt = 0; nt < NT; nt++) {
        int gc = col0 + wn * (NT * 16) + nt * 16 + l15;
        if (EPI == 0) {
            float cwl = wl[gc], cwh = wh[gc], cbh = bhr[gc], cbj = bj[gc];
            #pragma unroll
            for (int mt = 0; mt < 4; mt++) {
                #pragma unroll
                for (int r = 0; r < 4; r++) {
                    float m = acc[mt][nt][r];
                    float t, bt;
                    if (is_high) { t = (m > 0.f) ? m * cwh : m * cwl; bt = fmaxf(m, 0.f) * cbh; }
                    else         { t = (m > 0.f) ? m * cwl : m * cwh; bt = fminf(m, 0.f) * cbh; }
                    bsum[mt][r] += bt + t * cbj;
                    int grow = row0 + wm * 64 + mt * 16 + lq * 4 + r;
                    size_t o = (size_t)grow * 2048 + gc;
                    _Float16 h = (_Float16)t;
                    oAh[o] = h;
                    oAl[o] = (_Float16)(t - (float)h);
                }
            }
        } else {
            float clo = lo0[gc], chi = hi0[gc];
            #pragma unroll
            for (int mt = 0; mt < 4; mt++) {
                #pragma unroll
                for (int r = 0; r < 4; r++) {
                    float m = acc[mt][nt][r];
                    float contrib;
                    if (is_high) contrib = (m < 0.f) ? m * clo : m * chi;
                    else         contrib = (m < 0.f) ? m * chi : m * clo;
                    bsum[mt][r] += contrib;
                }
            }
        }
    }
    #pragma unroll
    for (int mt = 0; mt < 4; mt++) {
        #pragma unroll
        for (int r = 0; r < 4; r++) {
            float v = bsum[mt][r];
            v += __shfl_xor(v, 1);
            v += __shfl_xor(v, 2);
            v += __shfl_xor(v, 4);
            v += __shfl_xor(v, 8);
            if (l15 == 0) {
                int grow = row0 + wm * 64 + mt * 16 + lq * 4 + r;
                if (EPI == 0) atomicAdd(&bias[grow], v);
                else          atomicAdd(&box[grow], v);
            }
        }
    }
}

// Layer-4 (20-row) prep: reduce split-K partials (or read W4 bcast), apply
// relu-backsub record, write fp32 [20,2048] (ld 2048), update bias20.
__global__ void k_prep20(const float* __restrict__ Pin, int srcmod, int nparts,
                         const float* __restrict__ wl, const float* __restrict__ wh,
                         const float* __restrict__ bhr, const float* __restrict__ bj,
                         float* __restrict__ bias20, const float* __restrict__ binit,
                         float* __restrict__ Pout) {
    int row = blockIdx.x;
    int srow = (srcmod == 10) ? (row % 10) : row;
    int is_high = row < 10;
    float acc = 0.f;
    for (int c = threadIdx.x; c < 2048; c += 256) {
        float m = 0.f;
        for (int p = 0; p < nparts; p++)
            m += Pin[(size_t)p * 40960 + (size_t)srow * 2048 + c];
        float t, bt;
        if (is_high) { t = (m > 0.f) ? m * wh[c] : m * wl[c]; bt = fmaxf(m, 0.f) * bhr[c]; }
        else         { t = (m > 0.f) ? m * wl[c] : m * wh[c]; bt = fminf(m, 0.f) * bhr[c]; }
        acc += bt + t * bj[c];
        Pout[(size_t)row * 2048 + c] = t;
    }
    acc = blockReduce256(acc);
    if (threadIdx.x == 0)
        bias20[row] = (binit ? binit[srow] : bias20[row]) + acc;
}

// Split-K skinny: Ppart[ky][20][*] (ld 2048) = A[20, ky-slice] @ W[slice, N].
__global__ __launch_bounds__(256) void k_skinny(const float* __restrict__ A,
                                                const float* __restrict__ W, int N,
                                                float* __restrict__ Ppart) {
    __shared__ float sA[20 * 256];
    __shared__ float sRed[20 * 128];
    int ky = blockIdx.y, k0 = ky * 256;
    int tid = threadIdx.x;
    for (int idx = tid; idx < 20 * 256; idx += 256) {
        int r = idx >> 8, k = idx & 255;
        sA[idx] = A[(size_t)r * 2048 + k0 + k];
    }
    __syncthreads();
    int c = blockIdx.x * 128 + (tid & 127);
    int kh = tid >> 7;
    float acc[20];
    #pragma unroll
    for (int r = 0; r < 20; r++) acc[r] = 0.f;
    if (c < N) {
        const float* Wp = W + (size_t)(k0 + kh * 128) * N + c;
        for (int kk = 0; kk < 128; kk++) {
            float w = Wp[(size_t)kk * N];
            #pragma unroll
            for (int r = 0; r < 20; r++) acc[r] += sA[r * 256 + kh * 128 + kk] * w;
        }
    }
    if (kh == 1 && c < N) {
        #pragma unroll
        for (int r = 0; r < 20; r++) sRed[r * 128 + (tid & 127)] = acc[r];
    }
    __syncthreads();
    if (kh == 0 && c < N) {
        #pragma unroll
        for (int r = 0; r < 20; r++)
            Ppart[(size_t)ky * 40960 + (size_t)r * 2048 + c] =
                acc[r] + sRed[r * 128 + (tid & 127)];
    }
}

// Final layer-4 interval matvec from 8 split-K parts.
__global__ void k_fbox20(const float* __restrict__ Ppart,
                         const float* __restrict__ bias20,
                         const float* __restrict__ lo0, const float* __restrict__ hi0,
                         float* __restrict__ out) {
    int row = blockIdx.x;
    int is_high = row < 10;
    float acc = 0.f;
    for (int c = threadIdx.x; c < 784; c += 256) {
        float m = 0.f;
        #pragma unroll
        for (int p = 0; p < 8; p++)
            m += Ppart[(size_t)p * 40960 + (size_t)row * 2048 + c];
        if (is_high) acc += (m < 0.f) ? m * lo0[c] : m * hi0[c];
        else         acc += (m < 0.f) ? m * hi0[c] : m * lo0[c];
    }
    acc = blockReduce256(acc);
    if (threadIdx.x == 0) {
        float v = acc + bias20[row];
        out[is_high ? (20 + row) : row] = v;  // row>=10 -> out[10..19] (low)
    }
}

// Relu record capture; reads BOX (high=BOX[i], low=BOX[2048+i]).
__global__ void k_relu_rec(float* __restrict__ x, const float* __restrict__ box,
                           float* __restrict__ wl, float* __restrict__ wh,
                           float* __restrict__ bhr) {
    int i = blockIdx.x * blockDim.x + threadIdx.x;
    float h = box[i], l = box[2048 + i];
    float vwl, vwh, vbh;
    if (h <= 0.f)      { vwl = 0.f; vwh = 0.f; vbh = 0.f; }
    else if (l >= 0.f) { vwl = 1.f; vwh = 1.f; vbh = 0.f; }
    else {
        float d = h - l;
        vwh = h / d;
        vbh = -(l * h) / d;
        vwl = (l * l > h * h) ? 0.f : 1.f;
    }
    wl[i] = vwl; wh[i] = vwh; bhr[i] = vbh;
    x[i] = fmaxf(x[i], 0.f);
}

extern "C" void kernel_launch(void* const* d_in, const int* in_sizes, int n_in,
                              void* d_out, int out_size, void* d_ws, size_t ws_size,
                              hipStream_t stream) {
    const float* x_in  = (const float*)d_in[0];
    const float* lo_in = (const float*)d_in[1];
    const float* hi_in = (const float*)d_in[2];
    const float* W[5];
    const float* bv[5];
    for (int i = 0; i < 5; i++) {
        W[i]  = (const float*)d_in[3 + 2 * i];
        bv[i] = (const float*)d_in[4 + 2 * i];
    }
    float* ws = (float*)d_ws;
    float* out = (float*)d_out;

    float* X[2]   = {ws + OFF_X0, ws + OFF_X1};
    float* lo0    = ws + OFF_L0;
    float* hi0    = ws + OFF_H0;
    float* box    = ws + OFF_BOX;
    float* bias   = ws + OFF_BIAS;
    float* b20    = ws + OFF_B20;
    float* PC     = ws + OFF_PC;
    float* PP     = ws + OFF_PP;
    _Float16* WTh = (_Float16*)(ws + OFF_WTH);
    _Float16* WTl = (_Float16*)(ws + OFF_WTL);
    _Float16* AH[2] = {(_Float16*)(ws + OFF_AH0), (_Float16*)(ws + OFF_AH1)};
    _Float16* AL[2] = {(_Float16*)(ws + OFF_AL0), (_Float16*)(ws + OFF_AL1)};
    float* WLr = ws + OFF_WL;
    float* WHr = ws + OFF_WH;
    float* BHr = ws + OFF_BHR;

    k_norm<<<4, 256, 0, stream>>>(x_in, lo_in, hi_in, ws);

    // ---- layer 0 ----
    k_matvec<<<2048, 256, 0, stream>>>(W[0], X[0], bv[0], X[1], 784);
    k_fboxes0<<<4096, 256, 0, stream>>>(W[0], bv[0], lo0, hi0, box);
    k_relu_rec<<<8, 256, 0, stream>>>(X[1], box, WLr, WHr, BHr);

    // ---- layers 1..3: stacked MFMA chains with fused epilogues ----
    int cur = 1;
    for (int i = 1; i <= 3; i++) {
        int nxt = cur ^ 1;
        k_matvec<<<2048, 256, 0, stream>>>(W[i], X[cur], bv[i], X[nxt], 2048);
        // first step: T_{i-1}(W_i) -> AH[0]/AL[0], bias = bv_i + terms
        k_relu_split<<<4096, 256, 0, stream>>>(
            W[i], WLr + (i - 1) * 2048, WHr + (i - 1) * 2048,
            BHr + (i - 1) * 2048, bv[i - 1], bias, bv[i], AH[0], AL[0]);
        int p = 0;
        // middle steps j = i-1 .. 1: GEMM with T_{j-1} epilogue
        for (int j = i - 1; j >= 1; j--) {
            k_transpose_split<<<dim3(64, 64), 256, 0, stream>>>(W[j], 2048, WTh, WTl);
            k_gemm<4, 0><<<dim3(16, 32), 256, 0, stream>>>(
                AH[p], AL[p], WTh, WTl,
                WLr + (j - 1) * 2048, WHr + (j - 1) * 2048,
                BHr + (j - 1) * 2048, bv[j - 1], bias,
                AH[p ^ 1], AL[p ^ 1], nullptr, nullptr, nullptr);
            p ^= 1;
        }
        // last step j=0: GEMM with interval-matvec epilogue into BOX
        k_transpose_split<<<dim3(28, 64), 256, 0, stream>>>(W[0], 784, WTh, WTl);
        k_initbox<<<16, 256, 0, stream>>>(bias, box);
        k_gemm<2, 1><<<dim3(14, 32), 256, 0, stream>>>(
            AH[p], AL[p], WTh, WTl,
            nullptr, nullptr, nullptr, nullptr, nullptr,
            nullptr, nullptr, lo0, hi0, box);
        k_relu_rec<<<8, 256, 0, stream>>>(X[nxt], box,
                                          WLr + i * 2048, WHr + i * 2048,
                                          BHr + i * 2048);
        cur = nxt;
    }

    // ---- layer 4: 20-row chains (split-K partial path) ----
    k_matvec<<<10, 256, 0, stream>>>(W[4], X[cur], bv[4], out, 2048);
    // j=3
    k_prep20<<<20, 256, 0, stream>>>(W[4], 10, 1,
        WLr + 3 * 2048, WHr + 3 * 2048, BHr + 3 * 2048, bv[3], b20, bv[4], PC);
    k_skinny<<<dim3(16, 8), 256, 0, stream>>>(PC, W[3], 2048, PP);
    // j=2
    k_prep20<<<20, 256, 0, stream>>>(PP, 20, 8,
        WLr + 2 * 2048, WHr + 2 * 2048, BHr + 2 * 2048, bv[2], b20, nullptr, PC);
    k_skinny<<<dim3(16, 8), 256, 0, stream>>>(PC, W[2], 2048, PP);
    // j=1
    k_prep20<<<20, 256, 0, stream>>>(PP, 20, 8,
        WLr + 1 * 2048, WHr + 1 * 2048, BHr + 1 * 2048, bv[1], b20, nullptr, PC);
    k_skinny<<<dim3(16, 8), 256, 0, stream>>>(PC, W[1], 2048, PP);
    // j=0
    k_prep20<<<20, 256, 0, stream>>>(PP, 20, 8,
        WLr + 0 * 2048, WHr + 0 * 2048, BHr + 0 * 2048, bv[0], b20, nullptr, PC);
    k_skinny<<<dim3(7, 8), 256, 0, stream>>>(PC, W[0], 784, PP);
    k_fbox20<<<20, 256, 0, stream>>>(PP, b20, lo0, hi0, out);
}

// Round 6
// 929.246 us; speedup vs baseline: 6.0573x; 1.0468x over previous
//
#include <hip/hip_runtime.h>
#include <hip/hip_bf16.h>

// DeepPoly MLP verifier (784->2048x4->10).
// Round 6: double-buffered LDS K-loop in the f16 hi/lo 3-product MFMA GEMM
// (stage k+1 AFTER the barrier -> the barrier's vmcnt(0) drains loads that
// are a full compute-phase old: kills the 2-blocks/CU barrier-drain stall).
// Dispatch diet: forward matvec fused into relu_split/fboxes0; initbox
// replaced by memset + bias-add in relu_rec; layer-4 prep fused into the
// split-K skinny GEMM + single bias kernel. 31 dispatches (was ~45).

#define MEAN_C 0.1307f
#define STD_C  0.3081f

// ---- workspace offsets (floats), total ~89.3 MB ----
#define OFF_X0     0u
#define OFF_X1     2048u
#define OFF_L0     4096u       // 896 used (zero-padded)
#define OFF_H0     5120u
#define OFF_WL     6144u       // 4*2048
#define OFF_WH     14336u
#define OFF_BHR    22528u
#define OFF_BOX    30720u      // 4096 high/low
#define OFF_BIAS   34816u      // 4096
#define OFF_B20    38912u      // 32
#define OFF_PPA    38944u      // 8*20*2048
#define OFF_PPB    366624u
#define OFF_PPC    694304u
#define OFF_PPD    1021984u
#define OFF_WTH    1349664u    // f16 [<=2048][2048]
#define OFF_WTL    3446816u
#define OFF_AH0    5543968u    // f16 [4096][2048]
#define OFF_AL0    9738272u
#define OFF_AH1    13932576u
#define OFF_AL1    18126880u
// end 22321184 floats

typedef _Float16 half8 __attribute__((ext_vector_type(8)));
typedef float floatx4 __attribute__((ext_vector_type(4)));

__device__ __forceinline__ void gl2lds16(const void* g, void* l) {
    __builtin_amdgcn_global_load_lds(
        (const __attribute__((address_space(1))) unsigned int*)g,
        (__attribute__((address_space(3))) unsigned int*)l, 16, 0, 0);
}

__device__ __forceinline__ float blockReduce256(float v) {
    #pragma unroll
    for (int o = 32; o > 0; o >>= 1) v += __shfl_down(v, o, 64);
    __shared__ float sred[4];
    int w = threadIdx.x >> 6;
    if ((threadIdx.x & 63) == 0) sred[w] = v;
    __syncthreads();
    float r = 0.f;
    if (threadIdx.x == 0) r = sred[0] + sred[1] + sred[2] + sred[3];
    return r;
}

__device__ __forceinline__ float2 blockReduce256x2(float a, float b) {
    #pragma unroll
    for (int o = 32; o > 0; o >>= 1) {
        a += __shfl_down(a, o, 64);
        b += __shfl_down(b, o, 64);
    }
    __shared__ float sa[4], sb[4];
    int w = threadIdx.x >> 6;
    if ((threadIdx.x & 63) == 0) { sa[w] = a; sb[w] = b; }
    __syncthreads();
    float2 r = {0.f, 0.f};
    if (threadIdx.x == 0) {
        r.x = sa[0] + sa[1] + sa[2] + sa[3];
        r.y = sb[0] + sb[1] + sb[2] + sb[3];
    }
    return r;
}

__global__ void k_norm(const float* __restrict__ x, const float* __restrict__ lo,
                       const float* __restrict__ hi, float* __restrict__ ws) {
    int i = blockIdx.x * blockDim.x + threadIdx.x;
    if (i < 784) {
        ws[OFF_X0 + i] = (x[i]  - MEAN_C) / STD_C;
        ws[OFF_L0 + i] = (lo[i] - MEAN_C) / STD_C;
        ws[OFF_H0 + i] = (hi[i] - MEAN_C) / STD_C;
    } else if (i < 896) {
        ws[OFF_L0 + i] = 0.f;
        ws[OFF_H0 + i] = 0.f;
    }
}

__global__ void k_matvec(const float* __restrict__ W, const float* __restrict__ x,
                         const float* __restrict__ b, float* __restrict__ y, int k) {
    int r = blockIdx.x;
    const float* Wr = W + (size_t)r * k;
    float acc = 0.f;
    for (int c = threadIdx.x; c < k; c += 256) acc += Wr[c] * x[c];
    acc = blockReduce256(acc);
    if (threadIdx.x == 0) y[r] = acc + b[r];
}

// Layer-0 interval matvec + forward matvec fused (both read the same W0 row).
__global__ void k_fboxes0(const float* __restrict__ W0, const float* __restrict__ b0,
                          const float* __restrict__ x0,
                          const float* __restrict__ lo0, const float* __restrict__ hi0,
                          float* __restrict__ box, float* __restrict__ xout) {
    int r = blockIdx.x;
    int srow = r & 2047;
    int is_high = r < 2048;
    const float* Wr = W0 + (size_t)srow * 784;
    float acc = 0.f, accx = 0.f;
    for (int c = threadIdx.x; c < 784; c += 256) {
        float m = Wr[c];
        if (is_high) acc += (m < 0.f) ? m * lo0[c] : m * hi0[c];
        else         acc += (m < 0.f) ? m * hi0[c] : m * lo0[c];
        accx += m * x0[c];
    }
    float2 rr = blockReduce256x2(acc, accx);
    if (threadIdx.x == 0) {
        box[r] = rr.x + b0[srow];
        if (is_high) xout[r] = rr.y + b0[r];
    }
}

// First backsub step + forward matvec fused: T_{i-1}(W_i) stacked (4096 rows)
// -> f16 hi/lo A; bias = bv_i + terms; rows<2048 also compute y = W_i@x + bv_i.
__global__ __launch_bounds__(256) void k_relu_split(
        const float* __restrict__ Wi, const float* __restrict__ xin,
        const float* __restrict__ wl, const float* __restrict__ wh,
        const float* __restrict__ bhr, const float* __restrict__ bj,
        const float* __restrict__ bvi, float* __restrict__ bias,
        float* __restrict__ xout,
        _Float16* __restrict__ Ahi, _Float16* __restrict__ Alo) {
    int row = blockIdx.x;
    int is_high = row < 2048;
    int srow = row & 2047;
    const float* src = Wi + (size_t)srow * 2048;
    int c0 = threadIdx.x * 8;
    float mv[8], awl[8], awh[8], ab[8], abj[8], ax[8];
    *(float4*)&mv[0]  = *(const float4*)(src + c0);
    *(float4*)&mv[4]  = *(const float4*)(src + c0 + 4);
    *(float4*)&awl[0] = *(const float4*)(wl + c0);
    *(float4*)&awl[4] = *(const float4*)(wl + c0 + 4);
    *(float4*)&awh[0] = *(const float4*)(wh + c0);
    *(float4*)&awh[4] = *(const float4*)(wh + c0 + 4);
    *(float4*)&ab[0]  = *(const float4*)(bhr + c0);
    *(float4*)&ab[4]  = *(const float4*)(bhr + c0 + 4);
    *(float4*)&abj[0] = *(const float4*)(bj + c0);
    *(float4*)&abj[4] = *(const float4*)(bj + c0 + 4);
    *(float4*)&ax[0]  = *(const float4*)(xin + c0);
    *(float4*)&ax[4]  = *(const float4*)(xin + c0 + 4);
    float acc = 0.f, accx = 0.f;
    half8 hi, lo;
    #pragma unroll
    for (int e = 0; e < 8; e++) {
        float m = mv[e];
        float t, bt;
        if (is_high) { t = (m > 0.f) ? m * awh[e] : m * awl[e]; bt = fmaxf(m, 0.f) * ab[e]; }
        else         { t = (m > 0.f) ? m * awl[e] : m * awh[e]; bt = fminf(m, 0.f) * ab[e]; }
        acc += bt + t * abj[e];
        accx += m * ax[e];
        _Float16 h = (_Float16)t;
        hi[e] = h;
        lo[e] = (_Float16)(t - (float)h);
    }
    *(half8*)(Ahi + (size_t)row * 2048 + c0) = hi;
    *(half8*)(Alo + (size_t)row * 2048 + c0) = lo;
    float2 rr = blockReduce256x2(acc, accx);
    if (threadIdx.x == 0) {
        bias[row] = bvi[srow] + rr.x;
        if (is_high) xout[row] = rr.y + bvi[row];
    }
}

// Transpose + f16 hi/lo split: Wt[n][k] = W[k][n]; pad n in [NC,NP) with 0.
__global__ void k_transpose_split(const float* __restrict__ W, int NC,
                                  _Float16* __restrict__ Thi,
                                  _Float16* __restrict__ Tlo) {
    __shared__ float s[32][33];
    int c = threadIdx.x & 31;
    int r = threadIdx.x >> 5;
    #pragma unroll
    for (int rr = 0; rr < 4; rr++) {
        int k = blockIdx.y * 32 + r + rr * 8;
        int n = blockIdx.x * 32 + c;
        float v = (n < NC) ? W[(size_t)k * NC + n] : 0.f;
        s[c][r + rr * 8] = v;
    }
    __syncthreads();
    #pragma unroll
    for (int rr = 0; rr < 4; rr++) {
        int nl = r + rr * 8;
        float v = s[nl][c];
        _Float16 h = (_Float16)v;
        size_t o = (size_t)(blockIdx.x * 32 + nl) * 2048 + blockIdx.y * 32 + c;
        Thi[o] = h;
        Tlo[o] = (_Float16)(v - (float)h);
    }
}

// C[4096,NP] = (Ah+Al) @ (Bh+Bl)^T, 3 f16 products, double-buffered LDS.
// BM=128, BN=NT*32, BK=32; 256 threads, 2x2 waves, wave tile 64x(NT*16).
// EPI 0: relu-backsub epilogue (emit next Ah/Al + bias atomics).
// EPI 1: interval-matvec epilogue (atomics into zero-initialized BOX).
template<int NT, int EPI>
__global__ __launch_bounds__(256, 2) void k_gemm(
        const _Float16* __restrict__ Ah, const _Float16* __restrict__ Al,
        const _Float16* __restrict__ Bh, const _Float16* __restrict__ Bl,
        const float* __restrict__ wl, const float* __restrict__ wh,
        const float* __restrict__ bhr, const float* __restrict__ bj,
        float* __restrict__ bias,
        _Float16* __restrict__ oAh, _Float16* __restrict__ oAl,
        const float* __restrict__ lo0, const float* __restrict__ hi0,
        float* __restrict__ box) {
    __shared__ _Float16 sA[2][2][4096];          // [buf][limb][128*32]
    __shared__ _Float16 sB[2][2][NT * 1024];     // [buf][limb][BN*32]
    int tid = threadIdx.x;
    int row0 = blockIdx.y * 128, col0 = blockIdx.x * (NT * 32);

    int cr = tid >> 2;
    int q  = (tid & 3) ^ (cr & 3);               // XOR bank swizzle at fetch
    const _Float16* gAh0 = Ah + (size_t)(row0 + cr) * 2048 + q * 8;
    const _Float16* gAh1 = gAh0 + (size_t)64 * 2048;
    const _Float16* gAl0 = Al + (size_t)(row0 + cr) * 2048 + q * 8;
    const _Float16* gAl1 = gAl0 + (size_t)64 * 2048;
    const _Float16* gBh0 = Bh + (size_t)(col0 + cr) * 2048 + q * 8;
    const _Float16* gBl0 = Bl + (size_t)(col0 + cr) * 2048 + q * 8;
    const _Float16* gBh1 = gBh0 + (size_t)64 * 2048;   // NT==4 only
    const _Float16* gBl1 = gBl0 + (size_t)64 * 2048;

    auto stage = [&](int k0, int b) {
        gl2lds16(gAh0 + k0, &sA[b][0][tid * 8]);
        gl2lds16(gAh1 + k0, &sA[b][0][tid * 8 + 2048]);
        gl2lds16(gAl0 + k0, &sA[b][1][tid * 8]);
        gl2lds16(gAl1 + k0, &sA[b][1][tid * 8 + 2048]);
        gl2lds16(gBh0 + k0, &sB[b][0][tid * 8]);
        gl2lds16(gBl0 + k0, &sB[b][1][tid * 8]);
        if (NT == 4) {
            gl2lds16(gBh1 + k0, &sB[b][0][tid * 8 + 2048]);
            gl2lds16(gBl1 + k0, &sB[b][1][tid * 8 + 2048]);
        }
    };

    int lane = tid & 63, wv = tid >> 6;
    int wm = wv & 1, wn = wv >> 1;
    int l15 = lane & 15, lq = lane >> 4;
    int soff = (lq ^ (l15 & 3)) * 8;
    int arow = wm * 64 + l15;
    int brow = wn * (NT * 16) + l15;

    floatx4 acc[4][NT];
    floatx4 z = {0.f, 0.f, 0.f, 0.f};
    #pragma unroll
    for (int i = 0; i < 4; i++)
        #pragma unroll
        for (int j = 0; j < NT; j++) acc[i][j] = z;

    stage(0, 0);
    for (int k0 = 0; k0 < 2048; k0 += 32) {
        int buf = (k0 >> 5) & 1;
        __syncthreads();                 // drains loads issued LAST iteration
        if (k0 + 32 < 2048) stage(k0 + 32, buf ^ 1);
        half8 bh[NT], bl[NT];
        #pragma unroll
        for (int nt = 0; nt < NT; nt++) {
            bh[nt] = *(const half8*)&sB[buf][0][(brow + nt * 16) * 32 + soff];
            bl[nt] = *(const half8*)&sB[buf][1][(brow + nt * 16) * 32 + soff];
        }
        #pragma unroll
        for (int mt = 0; mt < 4; mt++) {
            half8 ah = *(const half8*)&sA[buf][0][(arow + mt * 16) * 32 + soff];
            half8 al = *(const half8*)&sA[buf][1][(arow + mt * 16) * 32 + soff];
            #pragma unroll
            for (int nt = 0; nt < NT; nt++) {
                acc[mt][nt] = __builtin_amdgcn_mfma_f32_16x16x32_f16(ah, bh[nt], acc[mt][nt], 0, 0, 0);
                acc[mt][nt] = __builtin_amdgcn_mfma_f32_16x16x32_f16(al, bh[nt], acc[mt][nt], 0, 0, 0);
                acc[mt][nt] = __builtin_amdgcn_mfma_f32_16x16x32_f16(ah, bl[nt], acc[mt][nt], 0, 0, 0);
            }
        }
    }

    // C/D layout: col = lane&15, row = (lane>>4)*4 + reg
    int is_high = row0 < 2048;
    float bsum[4][4];
    #pragma unroll
    for (int mt = 0; mt < 4; mt++)
        #pragma unroll
        for (int r = 0; r < 4; r++) bsum[mt][r] = 0.f;

    #pragma unroll
    for (int nt = 0; nt < NT; nt++) {
        int gc = col0 + wn * (NT * 16) + nt * 16 + l15;
        if (EPI == 0) {
            float cwl = wl[gc], cwh = wh[gc], cbh = bhr[gc], cbj = bj[gc];
            #pragma unroll
            for (int mt = 0; mt < 4; mt++) {
                #pragma unroll
                for (int r = 0; r < 4; r++) {
                    float m = acc[mt][nt][r];
                    float t, bt;
                    if (is_high) { t = (m > 0.f) ? m * cwh : m * cwl; bt = fmaxf(m, 0.f) * cbh; }
                    else         { t = (m > 0.f) ? m * cwl : m * cwh; bt = fminf(m, 0.f) * cbh; }
                    bsum[mt][r] += bt + t * cbj;
                    int grow = row0 + wm * 64 + mt * 16 + lq * 4 + r;
                    size_t o = (size_t)grow * 2048 + gc;
                    _Float16 h = (_Float16)t;
                    oAh[o] = h;
                    oAl[o] = (_Float16)(t - (float)h);
                }
            }
        } else {
            float clo = lo0[gc], chi = hi0[gc];
            #pragma unroll
            for (int mt = 0; mt < 4; mt++) {
                #pragma unroll
                for (int r = 0; r < 4; r++) {
                    float m = acc[mt][nt][r];
                    float contrib;
                    if (is_high) contrib = (m < 0.f) ? m * clo : m * chi;
                    else         contrib = (m < 0.f) ? m * chi : m * clo;
                    bsum[mt][r] += contrib;
                }
            }
        }
    }
    #pragma unroll
    for (int mt = 0; mt < 4; mt++) {
        #pragma unroll
        for (int r = 0; r < 4; r++) {
            float v = bsum[mt][r];
            v += __shfl_xor(v, 1);
            v += __shfl_xor(v, 2);
            v += __shfl_xor(v, 4);
            v += __shfl_xor(v, 8);
            if (l15 == 0) {
                int grow = row0 + wm * 64 + mt * 16 + lq * 4 + r;
                if (EPI == 0) atomicAdd(&bias[grow], v);
                else          atomicAdd(&box[grow], v);
            }
        }
    }
}

// Layer-4 fused: reduce prev partials (or W4 bcast) + relu-backsub transform
// in prologue, then split-K skinny GEMM vs W[:,0:N]. Rows 0..9 high, 10..19 low.
__global__ __launch_bounds__(256) void k_skinny2(
        const float* __restrict__ src, int bcast,
        const float* __restrict__ wl, const float* __restrict__ wh,
        const float* __restrict__ W, int N, float* __restrict__ Ppart) {
    __shared__ float sA[20 * 256];
    __shared__ float sRed[20 * 128];
    int ky = blockIdx.y, k0 = ky * 256;
    int tid = threadIdx.x;
    for (int idx = tid; idx < 20 * 256; idx += 256) {
        int r = idx >> 8, c = idx & 255;
        int gc = k0 + c;
        float m;
        if (bcast) m = src[(size_t)(r % 10) * 2048 + gc];
        else {
            m = 0.f;
            #pragma unroll
            for (int p = 0; p < 8; p++)
                m += src[(size_t)p * 40960 + (size_t)r * 2048 + gc];
        }
        float t = (r < 10) ? ((m > 0.f) ? m * wh[gc] : m * wl[gc])
                           : ((m > 0.f) ? m * wl[gc] : m * wh[gc]);
        sA[idx] = t;
    }
    __syncthreads();
    int c = blockIdx.x * 128 + (tid & 127);
    int kh = tid >> 7;
    float acc[20];
    #pragma unroll
    for (int r = 0; r < 20; r++) acc[r] = 0.f;
    if (c < N) {
        const float* Wp = W + (size_t)(k0 + kh * 128) * N + c;
        for (int kk = 0; kk < 128; kk++) {
            float w = Wp[(size_t)kk * N];
            #pragma unroll
            for (int r = 0; r < 20; r++) acc[r] += sA[r * 256 + kh * 128 + kk] * w;
        }
    }
    if (kh == 1 && c < N) {
        #pragma unroll
        for (int r = 0; r < 20; r++) sRed[r * 128 + (tid & 127)] = acc[r];
    }
    __syncthreads();
    if (kh == 0 && c < N) {
        #pragma unroll
        for (int r = 0; r < 20; r++)
            Ppart[(size_t)ky * 40960 + (size_t)r * 2048 + c] =
                acc[r] + sRed[r * 128 + (tid & 127)];
    }
}

// All four layer-4 bias dots in one kernel: bias20 = bv4 + sum_j (bhr_j-dot +
// T_j(M_j)@b_j) with M_3=W4(bcast), M_2=sum PPa, M_1=sum PPb, M_0=sum PPc.
__global__ void k_bias20(const float* __restrict__ W4,
                         const float* __restrict__ PPa, const float* __restrict__ PPb,
                         const float* __restrict__ PPc,
                         const float* __restrict__ WLr, const float* __restrict__ WHr,
                         const float* __restrict__ BHr,
                         const float* __restrict__ b0, const float* __restrict__ b1,
                         const float* __restrict__ b2, const float* __restrict__ b3,
                         const float* __restrict__ b4,
                         float* __restrict__ bias20) {
    int row = blockIdx.x;
    int is_high = row < 10;
    int srow = row % 10;
    float acc = 0.f;
    for (int c = threadIdx.x; c < 2048; c += 256) {
        {   // rec3 on W4
            float m = W4[(size_t)srow * 2048 + c];
            float wlv = WLr[3 * 2048 + c], whv = WHr[3 * 2048 + c], bhv = BHr[3 * 2048 + c];
            float t  = is_high ? ((m > 0.f) ? m * whv : m * wlv) : ((m > 0.f) ? m * wlv : m * whv);
            float bt = is_high ? fmaxf(m, 0.f) * bhv : fminf(m, 0.f) * bhv;
            acc += bt + t * b3[c];
        }
        {   // rec2 on sum PPa
            float m = 0.f;
            #pragma unroll
            for (int p = 0; p < 8; p++) m += PPa[(size_t)p * 40960 + (size_t)row * 2048 + c];
            float wlv = WLr[2 * 2048 + c], whv = WHr[2 * 2048 + c], bhv = BHr[2 * 2048 + c];
            float t  = is_high ? ((m > 0.f) ? m * whv : m * wlv) : ((m > 0.f) ? m * wlv : m * whv);
            float bt = is_high ? fmaxf(m, 0.f) * bhv : fminf(m, 0.f) * bhv;
            acc += bt + t * b2[c];
        }
        {   // rec1 on sum PPb
            float m = 0.f;
            #pragma unroll
            for (int p = 0; p < 8; p++) m += PPb[(size_t)p * 40960 + (size_t)row * 2048 + c];
            float wlv = WLr[1 * 2048 + c], whv = WHr[1 * 2048 + c], bhv = BHr[1 * 2048 + c];
            float t  = is_high ? ((m > 0.f) ? m * whv : m * wlv) : ((m > 0.f) ? m * wlv : m * whv);
            float bt = is_high ? fmaxf(m, 0.f) * bhv : fminf(m, 0.f) * bhv;
            acc += bt + t * b1[c];
        }
        {   // rec0 on sum PPc
            float m = 0.f;
            #pragma unroll
            for (int p = 0; p < 8; p++) m += PPc[(size_t)p * 40960 + (size_t)row * 2048 + c];
            float wlv = WLr[c], whv = WHr[c], bhv = BHr[c];
            float t  = is_high ? ((m > 0.f) ? m * whv : m * wlv) : ((m > 0.f) ? m * wlv : m * whv);
            float bt = is_high ? fmaxf(m, 0.f) * bhv : fminf(m, 0.f) * bhv;
            acc += bt + t * b0[c];
        }
    }
    acc = blockReduce256(acc);
    if (threadIdx.x == 0) bias20[row] = b4[srow] + acc;
}

// Final layer-4 interval matvec from 8 split-K parts.
__global__ void k_fbox20(const float* __restrict__ Ppart,
                         const float* __restrict__ bias20,
                         const float* __restrict__ lo0, const float* __restrict__ hi0,
                         float* __restrict__ out) {
    int row = blockIdx.x;
    int is_high = row < 10;
    float acc = 0.f;
    for (int c = threadIdx.x; c < 784; c += 256) {
        float m = 0.f;
        #pragma unroll
        for (int p = 0; p < 8; p++)
            m += Ppart[(size_t)p * 40960 + (size_t)row * 2048 + c];
        if (is_high) acc += (m < 0.f) ? m * lo0[c] : m * hi0[c];
        else         acc += (m < 0.f) ? m * hi0[c] : m * lo0[c];
    }
    acc = blockReduce256(acc);
    if (threadIdx.x == 0) {
        float v = acc + bias20[row];
        out[is_high ? (20 + row) : row] = v;
    }
}

// Relu record capture; h/l = box (+ bias if given).
__global__ void k_relu_rec(float* __restrict__ x, const float* __restrict__ box,
                           const float* __restrict__ bias,
                           float* __restrict__ wl, float* __restrict__ wh,
                           float* __restrict__ bhr) {
    int i = blockIdx.x * blockDim.x + threadIdx.x;
    float h = box[i]        + (bias ? bias[i]        : 0.f);
    float l = box[2048 + i] + (bias ? bias[2048 + i] : 0.f);
    float vwl, vwh, vbh;
    if (h <= 0.f)      { vwl = 0.f; vwh = 0.f; vbh = 0.f; }
    else if (l >= 0.f) { vwl = 1.f; vwh = 1.f; vbh = 0.f; }
    else {
        float d = h - l;
        vwh = h / d;
        vbh = -(l * h) / d;
        vwl = (l * l > h * h) ? 0.f : 1.f;
    }
    wl[i] = vwl; wh[i] = vwh; bhr[i] = vbh;
    x[i] = fmaxf(x[i], 0.f);
}

extern "C" void kernel_launch(void* const* d_in, const int* in_sizes, int n_in,
                              void* d_out, int out_size, void* d_ws, size_t ws_size,
                              hipStream_t stream) {
    const float* x_in  = (const float*)d_in[0];
    const float* lo_in = (const float*)d_in[1];
    const float* hi_in = (const float*)d_in[2];
    const float* W[5];
    const float* bv[5];
    for (int i = 0; i < 5; i++) {
        W[i]  = (const float*)d_in[3 + 2 * i];
        bv[i] = (const float*)d_in[4 + 2 * i];
    }
    float* ws = (float*)d_ws;
    float* out = (float*)d_out;

    float* X[2]   = {ws + OFF_X0, ws + OFF_X1};
    float* lo0    = ws + OFF_L0;
    float* hi0    = ws + OFF_H0;
    float* box    = ws + OFF_BOX;
    float* bias   = ws + OFF_BIAS;
    float* b20    = ws + OFF_B20;
    float* PPa    = ws + OFF_PPA;
    float* PPb    = ws + OFF_PPB;
    float* PPc    = ws + OFF_PPC;
    float* PPd    = ws + OFF_PPD;
    _Float16* WTh = (_Float16*)(ws + OFF_WTH);
    _Float16* WTl = (_Float16*)(ws + OFF_WTL);
    _Float16* AH[2] = {(_Float16*)(ws + OFF_AH0), (_Float16*)(ws + OFF_AH1)};
    _Float16* AL[2] = {(_Float16*)(ws + OFF_AL0), (_Float16*)(ws + OFF_AL1)};
    float* WLr = ws + OFF_WL;
    float* WHr = ws + OFF_WH;
    float* BHr = ws + OFF_BHR;

    k_norm<<<4, 256, 0, stream>>>(x_in, lo_in, hi_in, ws);

    // ---- layer 0 (interval + forward fused) ----
    k_fboxes0<<<4096, 256, 0, stream>>>(W[0], bv[0], X[0], lo0, hi0, box, X[1]);
    k_relu_rec<<<8, 256, 0, stream>>>(X[1], box, nullptr, WLr, WHr, BHr);

    // ---- layers 1..3: stacked MFMA chains with fused epilogues ----
    int cur = 1;
    for (int i = 1; i <= 3; i++) {
        int nxt = cur ^ 1;
        // first step: T_{i-1}(W_i) -> AH[0]/AL[0]; bias init; forward matvec
        k_relu_split<<<4096, 256, 0, stream>>>(
            W[i], X[cur],
            WLr + (i - 1) * 2048, WHr + (i - 1) * 2048,
            BHr + (i - 1) * 2048, bv[i - 1], bv[i], bias, X[nxt], AH[0], AL[0]);
        hipMemsetAsync(box, 0, 4096 * sizeof(float), stream);
        int p = 0;
        for (int j = i - 1; j >= 1; j--) {
            k_transpose_split<<<dim3(64, 64), 256, 0, stream>>>(W[j], 2048, WTh, WTl);
            k_gemm<4, 0><<<dim3(16, 32), 256, 0, stream>>>(
                AH[p], AL[p], WTh, WTl,
                WLr + (j - 1) * 2048, WHr + (j - 1) * 2048,
                BHr + (j - 1) * 2048, bv[j - 1], bias,
                AH[p ^ 1], AL[p ^ 1], nullptr, nullptr, nullptr);
            p ^= 1;
        }
        k_transpose_split<<<dim3(28, 64), 256, 0, stream>>>(W[0], 784, WTh, WTl);
        k_gemm<2, 1><<<dim3(14, 32), 256, 0, stream>>>(
            AH[p], AL[p], WTh, WTl,
            nullptr, nullptr, nullptr, nullptr, nullptr,
            nullptr, nullptr, lo0, hi0, box);
        k_relu_rec<<<8, 256, 0, stream>>>(X[nxt], box, bias,
                                          WLr + i * 2048, WHr + i * 2048,
                                          BHr + i * 2048);
        cur = nxt;
    }

    // ---- layer 4: 20-row chains, fused split-K path ----
    k_matvec<<<10, 256, 0, stream>>>(W[4], X[cur], bv[4], out, 2048);
    k_skinny2<<<dim3(16, 8), 256, 0, stream>>>(W[4], 1,
        WLr + 3 * 2048, WHr + 3 * 2048, W[3], 2048, PPa);
    k_skinny2<<<dim3(16, 8), 256, 0, stream>>>(PPa, 0,
        WLr + 2 * 2048, WHr + 2 * 2048, W[2], 2048, PPb);
    k_skinny2<<<dim3(16, 8), 256, 0, stream>>>(PPb, 0,
        WLr + 1 * 2048, WHr + 1 * 2048, W[1], 2048, PPc);
    k_skinny2<<<dim3(7, 8), 256, 0, stream>>>(PPc, 0,
        WLr, WHr, W[0], 784, PPd);
    k_bias20<<<20, 256, 0, stream>>>(W[4], PPa, PPb, PPc,
        WLr, WHr, BHr, bv[0], bv[1], bv[2], bv[3], bv[4], b20);
    k_fbox20<<<20, 256, 0, stream>>>(PPd, b20, lo0, hi0, out);
}

// Round 7
// 906.769 us; speedup vs baseline: 6.2074x; 1.0248x over previous
//
#include <hip/hip_runtime.h>
#include <hip/hip_bf16.h>

// DeepPoly MLP verifier (784->2048x4->10).
// Round 7: GEMM reverted to round-5 single-buffer (dbuf regressed 120->135us).
// Dispatch diet: W0/W1/W2 transposed once up-front into persistent buffers;
// relu-records computed inline in k_relu_split from (box,bias) with block 0
// materializing the arrays; box/bias ping-pong (relu_split zeroes next box);
// layer-4 forward matvec folded into k_bias20. 21 dispatches (was 31).

#define MEAN_C 0.1307f
#define STD_C  0.3081f

// ---- workspace offsets (floats), total ~108.2 MB ----
#define OFF_X0     0u
#define OFF_X1     2048u
#define OFF_L0     4096u       // 896 used (zero-padded)
#define OFF_H0     5120u
#define OFF_WL     6144u       // 4*2048 (rec j at +j*2048)
#define OFF_WH     14336u
#define OFF_BHR    22528u
#define OFF_BOXA   30720u      // 4096
#define OFF_BOXB   34816u
#define OFF_BIASA  38912u      // 4096
#define OFF_BIASB  43008u
#define OFF_B20    47104u      // 32
#define OFF_W0TH   47136u      // f16 [896][2048]  = 917504 float-slots
#define OFF_W0TL   964640u
#define OFF_W1TH   1882144u    // f16 [2048][2048] = 2097152 float-slots
#define OFF_W1TL   3979296u
#define OFF_W2TH   6076448u
#define OFF_W2TL   8173600u
#define OFF_AH0    10270752u   // f16 [4096][2048] = 4194304 float-slots
#define OFF_AL0    14465056u
#define OFF_AH1    18659360u
#define OFF_AL1    22853664u
// PP split-K partials alias into AH1 (free during layer 4): 4 x 327680 floats
#define OFF_PPA    18659360u
#define OFF_PPB    18987040u
#define OFF_PPC    19314720u
#define OFF_PPD    19642400u
// end 27047968 floats

typedef _Float16 half8 __attribute__((ext_vector_type(8)));
typedef float floatx4 __attribute__((ext_vector_type(4)));

__device__ __forceinline__ void gl2lds16(const void* g, void* l) {
    __builtin_amdgcn_global_load_lds(
        (const __attribute__((address_space(1))) unsigned int*)g,
        (__attribute__((address_space(3))) unsigned int*)l, 16, 0, 0);
}

__device__ __forceinline__ float blockReduce256(float v) {
    #pragma unroll
    for (int o = 32; o > 0; o >>= 1) v += __shfl_down(v, o, 64);
    __shared__ float sred[4];
    int w = threadIdx.x >> 6;
    if ((threadIdx.x & 63) == 0) sred[w] = v;
    __syncthreads();
    float r = 0.f;
    if (threadIdx.x == 0) r = sred[0] + sred[1] + sred[2] + sred[3];
    return r;
}

__device__ __forceinline__ float2 blockReduce256x2(float a, float b) {
    #pragma unroll
    for (int o = 32; o > 0; o >>= 1) {
        a += __shfl_down(a, o, 64);
        b += __shfl_down(b, o, 64);
    }
    __shared__ float sa[4], sb[4];
    int w = threadIdx.x >> 6;
    if ((threadIdx.x & 63) == 0) { sa[w] = a; sb[w] = b; }
    __syncthreads();
    float2 r = {0.f, 0.f};
    if (threadIdx.x == 0) {
        r.x = sa[0] + sa[1] + sa[2] + sa[3];
        r.y = sb[0] + sb[1] + sb[2] + sb[3];
    }
    return r;
}

// DeepPoly relu relaxation from bounds (h,l).
__device__ __forceinline__ void relu_rec_calc(float h, float l,
                                              float& vwl, float& vwh, float& vbh) {
    if (h <= 0.f)      { vwl = 0.f; vwh = 0.f; vbh = 0.f; }
    else if (l >= 0.f) { vwl = 1.f; vwh = 1.f; vbh = 0.f; }
    else {
        float d = h - l;
        vwh = h / d;
        vbh = -(l * h) / d;
        vwl = (l * l > h * h) ? 0.f : 1.f;
    }
}

__global__ void k_norm(const float* __restrict__ x, const float* __restrict__ lo,
                       const float* __restrict__ hi, float* __restrict__ ws) {
    int i = blockIdx.x * blockDim.x + threadIdx.x;
    if (i < 784) {
        ws[OFF_X0 + i] = (x[i]  - MEAN_C) / STD_C;
        ws[OFF_L0 + i] = (lo[i] - MEAN_C) / STD_C;
        ws[OFF_H0 + i] = (hi[i] - MEAN_C) / STD_C;
    } else if (i < 896) {
        ws[OFF_L0 + i] = 0.f;
        ws[OFF_H0 + i] = 0.f;
    }
}

// Layer-0 interval matvec + forward matvec fused.
__global__ void k_fboxes0(const float* __restrict__ W0, const float* __restrict__ b0,
                          const float* __restrict__ x0,
                          const float* __restrict__ lo0, const float* __restrict__ hi0,
                          float* __restrict__ box, float* __restrict__ xout) {
    int r = blockIdx.x;
    int srow = r & 2047;
    int is_high = r < 2048;
    const float* Wr = W0 + (size_t)srow * 784;
    float acc = 0.f, accx = 0.f;
    for (int c = threadIdx.x; c < 784; c += 256) {
        float m = Wr[c];
        if (is_high) acc += (m < 0.f) ? m * lo0[c] : m * hi0[c];
        else         acc += (m < 0.f) ? m * hi0[c] : m * lo0[c];
        accx += m * x0[c];
    }
    float2 rr = blockReduce256x2(acc, accx);
    if (threadIdx.x == 0) {
        box[r] = rr.x + b0[srow];
        if (is_high) xout[r] = rr.y + b0[r];
    }
}

// First backsub step of layer i, with INLINE relu-record computation from
// (boxPrev, biasPrev): T_{i-1}(W_i) stacked (4096 rows) -> f16 hi/lo A;
// bias = bv_i + (bhr dot + T@b_{i-1}); block 0 materializes rec arrays;
// thread 0 zeroes boxOut[row]; rows<2048 also compute y = W_i@relu(x)+bv_i.
__global__ __launch_bounds__(256) void k_relu_split(
        const float* __restrict__ Wi, const float* __restrict__ xin,
        const float* __restrict__ boxPrev, const float* __restrict__ biasPrev,
        float* __restrict__ recWL, float* __restrict__ recWH, float* __restrict__ recBH,
        const float* __restrict__ bj, const float* __restrict__ bvi,
        float* __restrict__ bias, float* __restrict__ boxOut,
        float* __restrict__ xout,
        _Float16* __restrict__ Ahi, _Float16* __restrict__ Alo) {
    int row = blockIdx.x;
    int is_high = row < 2048;
    int srow = row & 2047;
    const float* src = Wi + (size_t)srow * 2048;
    int c0 = threadIdx.x * 8;
    float mv[8], bxh[8], bxl[8], abj[8], ax[8];
    *(float4*)&mv[0]  = *(const float4*)(src + c0);
    *(float4*)&mv[4]  = *(const float4*)(src + c0 + 4);
    *(float4*)&bxh[0] = *(const float4*)(boxPrev + c0);
    *(float4*)&bxh[4] = *(const float4*)(boxPrev + c0 + 4);
    *(float4*)&bxl[0] = *(const float4*)(boxPrev + 2048 + c0);
    *(float4*)&bxl[4] = *(const float4*)(boxPrev + 2048 + c0 + 4);
    *(float4*)&abj[0] = *(const float4*)(bj + c0);
    *(float4*)&abj[4] = *(const float4*)(bj + c0 + 4);
    *(float4*)&ax[0]  = *(const float4*)(xin + c0);
    *(float4*)&ax[4]  = *(const float4*)(xin + c0 + 4);
    if (biasPrev) {
        float ph[8], pl[8];
        *(float4*)&ph[0] = *(const float4*)(biasPrev + c0);
        *(float4*)&ph[4] = *(const float4*)(biasPrev + c0 + 4);
        *(float4*)&pl[0] = *(const float4*)(biasPrev + 2048 + c0);
        *(float4*)&pl[4] = *(const float4*)(biasPrev + 2048 + c0 + 4);
        #pragma unroll
        for (int e = 0; e < 8; e++) { bxh[e] += ph[e]; bxl[e] += pl[e]; }
    }
    float acc = 0.f, accx = 0.f;
    float rl[8], rh[8], rb[8];
    half8 hi, lo;
    #pragma unroll
    for (int e = 0; e < 8; e++) {
        relu_rec_calc(bxh[e], bxl[e], rl[e], rh[e], rb[e]);
        float m = mv[e];
        float t, bt;
        if (is_high) { t = (m > 0.f) ? m * rh[e] : m * rl[e]; bt = fmaxf(m, 0.f) * rb[e]; }
        else         { t = (m > 0.f) ? m * rl[e] : m * rh[e]; bt = fminf(m, 0.f) * rb[e]; }
        acc += bt + t * abj[e];
        accx += m * fmaxf(ax[e], 0.f);
        _Float16 h = (_Float16)t;
        hi[e] = h;
        lo[e] = (_Float16)(t - (float)h);
    }
    *(half8*)(Ahi + (size_t)row * 2048 + c0) = hi;
    *(half8*)(Alo + (size_t)row * 2048 + c0) = lo;
    if (row == 0) {   // materialize rec arrays for later consumers
        *(float4*)(recWL + c0) = *(float4*)&rl[0];
        *(float4*)(recWL + c0 + 4) = *(float4*)&rl[4];
        *(float4*)(recWH + c0) = *(float4*)&rh[0];
        *(float4*)(recWH + c0 + 4) = *(float4*)&rh[4];
        *(float4*)(recBH + c0) = *(float4*)&rb[0];
        *(float4*)(recBH + c0 + 4) = *(float4*)&rb[4];
    }
    float2 rr = blockReduce256x2(acc, accx);
    if (threadIdx.x == 0) {
        bias[row] = bvi[srow] + rr.x;
        boxOut[row] = 0.f;
        if (is_high) xout[row] = rr.y + bvi[row];
    }
}

// Transpose + f16 hi/lo split: Wt[n][k] = W[k][n]; pad n in [NC,NP) with 0.
__global__ void k_transpose_split(const float* __restrict__ W, int NC,
                                  _Float16* __restrict__ Thi,
                                  _Float16* __restrict__ Tlo) {
    __shared__ float s[32][33];
    int c = threadIdx.x & 31;
    int r = threadIdx.x >> 5;
    #pragma unroll
    for (int rr = 0; rr < 4; rr++) {
        int k = blockIdx.y * 32 + r + rr * 8;
        int n = blockIdx.x * 32 + c;
        float v = (n < NC) ? W[(size_t)k * NC + n] : 0.f;
        s[c][r + rr * 8] = v;
    }
    __syncthreads();
    #pragma unroll
    for (int rr = 0; rr < 4; rr++) {
        int nl = r + rr * 8;
        float v = s[nl][c];
        _Float16 h = (_Float16)v;
        size_t o = (size_t)(blockIdx.x * 32 + nl) * 2048 + blockIdx.y * 32 + c;
        Thi[o] = h;
        Tlo[o] = (_Float16)(v - (float)h);
    }
}

// C[4096,NP] = (Ah+Al) @ (Bh+Bl)^T, 3 f16 products, single-buffered LDS
// (round-5 proven; dbuf regressed). BM=128, BN=NT*32, BK=32; 256 threads.
// EPI 0: relu-backsub epilogue (emit next Ah/Al + bias atomics).
// EPI 1: interval-matvec epilogue (atomics into pre-zeroed BOX).
template<int NT, int EPI>
__global__ __launch_bounds__(256, 2) void k_gemm(
        const _Float16* __restrict__ Ah, const _Float16* __restrict__ Al,
        const _Float16* __restrict__ Bh, const _Float16* __restrict__ Bl,
        const float* __restrict__ wl, const float* __restrict__ wh,
        const float* __restrict__ bhr, const float* __restrict__ bj,
        float* __restrict__ bias,
        _Float16* __restrict__ oAh, _Float16* __restrict__ oAl,
        const float* __restrict__ lo0, const float* __restrict__ hi0,
        float* __restrict__ box) {
    __shared__ _Float16 sAh[128 * 32], sAl[128 * 32];
    __shared__ _Float16 sBh[NT * 32 * 32], sBl[NT * 32 * 32];
    int tid = threadIdx.x;
    int row0 = blockIdx.y * 128, col0 = blockIdx.x * (NT * 32);

    int cr = tid >> 2;
    int q  = (tid & 3) ^ (cr & 3);          // XOR bank swizzle at fetch
    const _Float16* gAh0 = Ah + (size_t)(row0 + cr) * 2048 + q * 8;
    const _Float16* gAh1 = gAh0 + (size_t)64 * 2048;
    const _Float16* gAl0 = Al + (size_t)(row0 + cr) * 2048 + q * 8;
    const _Float16* gAl1 = gAl0 + (size_t)64 * 2048;
    const _Float16* gBh0 = Bh + (size_t)(col0 + cr) * 2048 + q * 8;
    const _Float16* gBl0 = Bl + (size_t)(col0 + cr) * 2048 + q * 8;
    const _Float16* gBh1 = gBh0 + (size_t)64 * 2048;   // NT==4 only
    const _Float16* gBl1 = gBl0 + (size_t)64 * 2048;
    _Float16* lAh0 = &sAh[tid * 8];
    _Float16* lAh1 = &sAh[tid * 8 + 2048];
    _Float16* lAl0 = &sAl[tid * 8];
    _Float16* lAl1 = &sAl[tid * 8 + 2048];
    _Float16* lBh0 = &sBh[tid * 8];
    _Float16* lBl0 = &sBl[tid * 8];
    _Float16* lBh1 = &sBh[tid * 8 + 2048];
    _Float16* lBl1 = &sBl[tid * 8 + 2048];

    int lane = tid & 63, wv = tid >> 6;
    int wm = wv & 1, wn = wv >> 1;
    int l15 = lane & 15, lq = lane >> 4;
    int soff = (lq ^ (l15 & 3)) * 8;
    int arow = wm * 64 + l15;
    int brow = wn * (NT * 16) + l15;

    floatx4 acc[4][NT];
    floatx4 z = {0.f, 0.f, 0.f, 0.f};
    #pragma unroll
    for (int i = 0; i < 4; i++)
        #pragma unroll
        for (int j = 0; j < NT; j++) acc[i][j] = z;

    for (int k0 = 0; k0 < 2048; k0 += 32) {
        gl2lds16(gAh0 + k0, lAh0);
        gl2lds16(gAh1 + k0, lAh1);
        gl2lds16(gAl0 + k0, lAl0);
        gl2lds16(gAl1 + k0, lAl1);
        gl2lds16(gBh0 + k0, lBh0);
        gl2lds16(gBl0 + k0, lBl0);
        if (NT == 4) {
            gl2lds16(gBh1 + k0, lBh1);
            gl2lds16(gBl1 + k0, lBl1);
        }
        __syncthreads();
        half8 bh[NT], bl[NT];
        #pragma unroll
        for (int nt = 0; nt < NT; nt++) {
            bh[nt] = *(const half8*)&sBh[(brow + nt * 16) * 32 + soff];
            bl[nt] = *(const half8*)&sBl[(brow + nt * 16) * 32 + soff];
        }
        #pragma unroll
        for (int mt = 0; mt < 4; mt++) {
            half8 ah = *(const half8*)&sAh[(arow + mt * 16) * 32 + soff];
            half8 al = *(const half8*)&sAl[(arow + mt * 16) * 32 + soff];
            #pragma unroll
            for (int nt = 0; nt < NT; nt++) {
                acc[mt][nt] = __builtin_amdgcn_mfma_f32_16x16x32_f16(ah, bh[nt], acc[mt][nt], 0, 0, 0);
                acc[mt][nt] = __builtin_amdgcn_mfma_f32_16x16x32_f16(al, bh[nt], acc[mt][nt], 0, 0, 0);
                acc[mt][nt] = __builtin_amdgcn_mfma_f32_16x16x32_f16(ah, bl[nt], acc[mt][nt], 0, 0, 0);
            }
        }
        __syncthreads();
    }

    // C/D layout: col = lane&15, row = (lane>>4)*4 + reg
    int is_high = row0 < 2048;
    float bsum[4][4];
    #pragma unroll
    for (int mt = 0; mt < 4; mt++)
        #pragma unroll
        for (int r = 0; r < 4; r++) bsum[mt][r] = 0.f;

    #pragma unroll
    for (int nt = 0; nt < NT; nt++) {
        int gc = col0 + wn * (NT * 16) + nt * 16 + l15;
        if (EPI == 0) {
            float cwl = wl[gc], cwh = wh[gc], cbh = bhr[gc], cbj = bj[gc];
            #pragma unroll
            for (int mt = 0; mt < 4; mt++) {
                #pragma unroll
                for (int r = 0; r < 4; r++) {
                    float m = acc[mt][nt][r];
                    float t, bt;
                    if (is_high) { t = (m > 0.f) ? m * cwh : m * cwl; bt = fmaxf(m, 0.f) * cbh; }
                    else         { t = (m > 0.f) ? m * cwl : m * cwh; bt = fminf(m, 0.f) * cbh; }
                    bsum[mt][r] += bt + t * cbj;
                    int grow = row0 + wm * 64 + mt * 16 + lq * 4 + r;
                    size_t o = (size_t)grow * 2048 + gc;
                    _Float16 h = (_Float16)t;
                    oAh[o] = h;
                    oAl[o] = (_Float16)(t - (float)h);
                }
            }
        } else {
            float clo = lo0[gc], chi = hi0[gc];
            #pragma unroll
            for (int mt = 0; mt < 4; mt++) {
                #pragma unroll
                for (int r = 0; r < 4; r++) {
                    float m = acc[mt][nt][r];
                    float contrib;
                    if (is_high) contrib = (m < 0.f) ? m * clo : m * chi;
                    else         contrib = (m < 0.f) ? m * chi : m * clo;
                    bsum[mt][r] += contrib;
                }
            }
        }
    }
    #pragma unroll
    for (int mt = 0; mt < 4; mt++) {
        #pragma unroll
        for (int r = 0; r < 4; r++) {
            float v = bsum[mt][r];
            v += __shfl_xor(v, 1);
            v += __shfl_xor(v, 2);
            v += __shfl_xor(v, 4);
            v += __shfl_xor(v, 8);
            if (l15 == 0) {
                int grow = row0 + wm * 64 + mt * 16 + lq * 4 + r;
                if (EPI == 0) atomicAdd(&bias[grow], v);
                else          atomicAdd(&box[grow], v);
            }
        }
    }
}

// Rec3 capture only (layer-4 consumers read materialized arrays).
__global__ void k_relu_rec(const float* __restrict__ box, const float* __restrict__ bias,
                           float* __restrict__ wl, float* __restrict__ wh,
                           float* __restrict__ bhr) {
    int i = blockIdx.x * blockDim.x + threadIdx.x;
    float h = box[i] + bias[i];
    float l = box[2048 + i] + bias[2048 + i];
    float vwl, vwh, vbh;
    relu_rec_calc(h, l, vwl, vwh, vbh);
    wl[i] = vwl; wh[i] = vwh; bhr[i] = vbh;
}

// Layer-4 fused: reduce prev partials (or W4 bcast) + relu-backsub transform
// in prologue, then split-K skinny GEMM. Rows 0..9 high, 10..19 low.
__global__ __launch_bounds__(256) void k_skinny2(
        const float* __restrict__ src, int bcast,
        const float* __restrict__ wl, const float* __restrict__ wh,
        const float* __restrict__ W, int N, float* __restrict__ Ppart) {
    __shared__ float sA[20 * 256];
    __shared__ float sRed[20 * 128];
    int ky = blockIdx.y, k0 = ky * 256;
    int tid = threadIdx.x;
    for (int idx = tid; idx < 20 * 256; idx += 256) {
        int r = idx >> 8, c = idx & 255;
        int gc = k0 + c;
        float m;
        if (bcast) m = src[(size_t)(r % 10) * 2048 + gc];
        else {
            m = 0.f;
            #pragma unroll
            for (int p = 0; p < 8; p++)
                m += src[(size_t)p * 40960 + (size_t)r * 2048 + gc];
        }
        float t = (r < 10) ? ((m > 0.f) ? m * wh[gc] : m * wl[gc])
                           : ((m > 0.f) ? m * wl[gc] : m * wh[gc]);
        sA[idx] = t;
    }
    __syncthreads();
    int c = blockIdx.x * 128 + (tid & 127);
    int kh = tid >> 7;
    float acc[20];
    #pragma unroll
    for (int r = 0; r < 20; r++) acc[r] = 0.f;
    if (c < N) {
        const float* Wp = W + (size_t)(k0 + kh * 128) * N + c;
        for (int kk = 0; kk < 128; kk++) {
            float w = Wp[(size_t)kk * N];
            #pragma unroll
            for (int r = 0; r < 20; r++) acc[r] += sA[r * 256 + kh * 128 + kk] * w;
        }
    }
    if (kh == 1 && c < N) {
        #pragma unroll
        for (int r = 0; r < 20; r++) sRed[r * 128 + (tid & 127)] = acc[r];
    }
    __syncthreads();
    if (kh == 0 && c < N) {
        #pragma unroll
        for (int r = 0; r < 20; r++)
            Ppart[(size_t)ky * 40960 + (size_t)r * 2048 + c] =
                acc[r] + sRed[r * 128 + (tid & 127)];
    }
}

// All four layer-4 bias dots + the forward matvec (out[0..9]) in one kernel.
__global__ void k_bias20(const float* __restrict__ W4,
                         const float* __restrict__ PPa, const float* __restrict__ PPb,
                         const float* __restrict__ PPc,
                         const float* __restrict__ WLr, const float* __restrict__ WHr,
                         const float* __restrict__ BHr,
                         const float* __restrict__ b0, const float* __restrict__ b1,
                         const float* __restrict__ b2, const float* __restrict__ b3,
                         const float* __restrict__ b4,
                         const float* __restrict__ x3,
                         float* __restrict__ bias20, float* __restrict__ out) {
    int row = blockIdx.x;
    int is_high = row < 10;
    int srow = row % 10;
    float acc = 0.f, accx = 0.f;
    for (int c = threadIdx.x; c < 2048; c += 256) {
        {   // rec3 on W4 (+ forward matvec with relu'd x3)
            float m = W4[(size_t)srow * 2048 + c];
            float wlv = WLr[3 * 2048 + c], whv = WHr[3 * 2048 + c], bhv = BHr[3 * 2048 + c];
            float t  = is_high ? ((m > 0.f) ? m * whv : m * wlv) : ((m > 0.f) ? m * wlv : m * whv);
            float bt = is_high ? fmaxf(m, 0.f) * bhv : fminf(m, 0.f) * bhv;
            acc += bt + t * b3[c];
            accx += m * fmaxf(x3[c], 0.f);
        }
        {   // rec2 on sum PPa
            float m = 0.f;
            #pragma unroll
            for (int p = 0; p < 8; p++) m += PPa[(size_t)p * 40960 + (size_t)row * 2048 + c];
            float wlv = WLr[2 * 2048 + c], whv = WHr[2 * 2048 + c], bhv = BHr[2 * 2048 + c];
            float t  = is_high ? ((m > 0.f) ? m * whv : m * wlv) : ((m > 0.f) ? m * wlv : m * whv);
            float bt = is_high ? fmaxf(m, 0.f) * bhv : fminf(m, 0.f) * bhv;
            acc += bt + t * b2[c];
        }
        {   // rec1 on sum PPb
            float m = 0.f;
            #pragma unroll
            for (int p = 0; p < 8; p++) m += PPb[(size_t)p * 40960 + (size_t)row * 2048 + c];
            float wlv = WLr[1 * 2048 + c], whv = WHr[1 * 2048 + c], bhv = BHr[1 * 2048 + c];
            float t  = is_high ? ((m > 0.f) ? m * whv : m * wlv) : ((m > 0.f) ? m * wlv : m * whv);
            float bt = is_high ? fmaxf(m, 0.f) * bhv : fminf(m, 0.f) * bhv;
            acc += bt + t * b1[c];
        }
        {   // rec0 on sum PPc
            float m = 0.f;
            #pragma unroll
            for (int p = 0; p < 8; p++) m += PPc[(size_t)p * 40960 + (size_t)row * 2048 + c];
            float wlv = WLr[c], whv = WHr[c], bhv = BHr[c];
            float t  = is_high ? ((m > 0.f) ? m * whv : m * wlv) : ((m > 0.f) ? m * wlv : m * whv);
            float bt = is_high ? fmaxf(m, 0.f) * bhv : fminf(m, 0.f) * bhv;
            acc += bt + t * b0[c];
        }
    }
    float2 rr = blockReduce256x2(acc, accx);
    if (threadIdx.x == 0) {
        bias20[row] = b4[srow] + rr.x;
        if (is_high) out[row] = b4[row] + rr.y;
    }
}

// Final layer-4 interval matvec from 8 split-K parts.
__global__ void k_fbox20(const float* __restrict__ Ppart,
                         const float* __restrict__ bias20,
                         const float* __restrict__ lo0, const float* __restrict__ hi0,
                         float* __restrict__ out) {
    int row = blockIdx.x;
    int is_high = row < 10;
    float acc = 0.f;
    for (int c = threadIdx.x; c < 784; c += 256) {
        float m = 0.f;
        #pragma unroll
        for (int p = 0; p < 8; p++)
            m += Ppart[(size_t)p * 40960 + (size_t)row * 2048 + c];
        if (is_high) acc += (m < 0.f) ? m * lo0[c] : m * hi0[c];
        else         acc += (m < 0.f) ? m * hi0[c] : m * lo0[c];
    }
    acc = blockReduce256(acc);
    if (threadIdx.x == 0) {
        float v = acc + bias20[row];
        out[is_high ? (20 + row) : row] = v;
    }
}

extern "C" void kernel_launch(void* const* d_in, const int* in_sizes, int n_in,
                              void* d_out, int out_size, void* d_ws, size_t ws_size,
                              hipStream_t stream) {
    const float* x_in  = (const float*)d_in[0];
    const float* lo_in = (const float*)d_in[1];
    const float* hi_in = (const float*)d_in[2];
    const float* W[5];
    const float* bv[5];
    for (int i = 0; i < 5; i++) {
        W[i]  = (const float*)d_in[3 + 2 * i];
        bv[i] = (const float*)d_in[4 + 2 * i];
    }
    float* ws = (float*)d_ws;
    float* out = (float*)d_out;

    float* X[2]    = {ws + OFF_X0, ws + OFF_X1};
    float* lo0     = ws + OFF_L0;
    float* hi0     = ws + OFF_H0;
    float* BOX[2]  = {ws + OFF_BOXA, ws + OFF_BOXB};
    float* BIAS[2] = {ws + OFF_BIASA, ws + OFF_BIASB};
    float* b20     = ws + OFF_B20;
    float* PPa     = ws + OFF_PPA;
    float* PPb     = ws + OFF_PPB;
    float* PPc     = ws + OFF_PPC;
    float* PPd     = ws + OFF_PPD;
    _Float16* WT_H[3] = {(_Float16*)(ws + OFF_W0TH), (_Float16*)(ws + OFF_W1TH),
                         (_Float16*)(ws + OFF_W2TH)};
    _Float16* WT_L[3] = {(_Float16*)(ws + OFF_W0TL), (_Float16*)(ws + OFF_W1TL),
                         (_Float16*)(ws + OFF_W2TL)};
    _Float16* AH[2] = {(_Float16*)(ws + OFF_AH0), (_Float16*)(ws + OFF_AH1)};
    _Float16* AL[2] = {(_Float16*)(ws + OFF_AL0), (_Float16*)(ws + OFF_AL1)};
    float* WLr = ws + OFF_WL;
    float* WHr = ws + OFF_WH;
    float* BHr = ws + OFF_BHR;

    k_norm<<<4, 256, 0, stream>>>(x_in, lo_in, hi_in, ws);
    // hoisted transposes (input-only dependencies)
    k_transpose_split<<<dim3(28, 64), 256, 0, stream>>>(W[0], 784, WT_H[0], WT_L[0]);
    k_transpose_split<<<dim3(64, 64), 256, 0, stream>>>(W[1], 2048, WT_H[1], WT_L[1]);
    k_transpose_split<<<dim3(64, 64), 256, 0, stream>>>(W[2], 2048, WT_H[2], WT_L[2]);

    // ---- layer 0 ----
    k_fboxes0<<<4096, 256, 0, stream>>>(W[0], bv[0], X[0], lo0, hi0, BOX[0], X[1]);

    // ---- layers 1..3 ----
    int xcur = 1, bprev = 0;   // BOX[bprev] = prev layer bounds; bias ping-pong
    const float* biasPrev = nullptr;
    for (int i = 1; i <= 3; i++) {
        int xnxt = xcur ^ 1;
        int bcur = bprev ^ 1;
        float* biasCur = BIAS[(i - 1) & 1];
        k_relu_split<<<4096, 256, 0, stream>>>(
            W[i], X[xcur], BOX[bprev], biasPrev,
            WLr + (i - 1) * 2048, WHr + (i - 1) * 2048, BHr + (i - 1) * 2048,
            bv[i - 1], bv[i], biasCur, BOX[bcur], X[xnxt], AH[0], AL[0]);
        int p = 0;
        for (int j = i - 1; j >= 1; j--) {
            k_gemm<4, 0><<<dim3(16, 32), 256, 0, stream>>>(
                AH[p], AL[p], WT_H[j], WT_L[j],
                WLr + (j - 1) * 2048, WHr + (j - 1) * 2048,
                BHr + (j - 1) * 2048, bv[j - 1], biasCur,
                AH[p ^ 1], AL[p ^ 1], nullptr, nullptr, nullptr);
            p ^= 1;
        }
        k_gemm<2, 1><<<dim3(14, 32), 256, 0, stream>>>(
            AH[p], AL[p], WT_H[0], WT_L[0],
            nullptr, nullptr, nullptr, nullptr, nullptr,
            nullptr, nullptr, lo0, hi0, BOX[bcur]);
        biasPrev = biasCur;
        bprev = bcur;
        xcur = xnxt;
    }
    // rec3 for the layer-4 path (BIAS[(3-1)&1] = BIAS[0])
    k_relu_rec<<<8, 256, 0, stream>>>(BOX[bprev], BIAS[0],
                                      WLr + 3 * 2048, WHr + 3 * 2048, BHr + 3 * 2048);

    // ---- layer 4: 20-row chains (split-K partial path) ----
    k_skinny2<<<dim3(16, 8), 256, 0, stream>>>(W[4], 1,
        WLr + 3 * 2048, WHr + 3 * 2048, W[3], 2048, PPa);
    k_skinny2<<<dim3(16, 8), 256, 0, stream>>>(PPa, 0,
        WLr + 2 * 2048, WHr + 2 * 2048, W[2], 2048, PPb);
    k_skinny2<<<dim3(16, 8), 256, 0, stream>>>(PPb, 0,
        WLr + 1 * 2048, WHr + 1 * 2048, W[1], 2048, PPc);
    k_skinny2<<<dim3(7, 8), 256, 0, stream>>>(PPc, 0,
        WLr, WHr, W[0], 784, PPd);
    k_bias20<<<20, 256, 0, stream>>>(W[4], PPa, PPb, PPc,
        WLr, WHr, BHr, bv[0], bv[1], bv[2], bv[3], bv[4], X[xcur], b20, out);
    k_fbox20<<<20, 256, 0, stream>>>(PPd, b20, lo0, hi0, out);
}